// Round 1
// baseline (444.225 us; speedup 1.0000x reference)
//
#include <hip/hip_runtime.h>
#include <hip/hip_bf16.h>

typedef unsigned short u16;
typedef __attribute__((ext_vector_type(4))) unsigned short u16x4;
typedef __attribute__((ext_vector_type(8))) unsigned short u16x8;
typedef __attribute__((ext_vector_type(8))) __bf16 bf16x8;
typedef __attribute__((ext_vector_type(4))) float f32x4;

typedef __attribute__((address_space(1))) void as1v;
typedef __attribute__((address_space(3))) void as3v;

#define MFMA16(a, b, c) __builtin_amdgcn_mfma_f32_16x16x32_bf16(a, b, c, 0, 0, 0)

__device__ __forceinline__ u16 f2bf(float f) {
    unsigned u = __builtin_bit_cast(unsigned, f);
    u += 0x7fffu + ((u >> 16) & 1u);
    return (u16)(u >> 16);
}

__device__ __forceinline__ void gload16(const void* g, void* l) {
    __builtin_amdgcn_global_load_lds((as1v*)g, (as3v*)l, 16, 0, 0);
}

// ---------------------------------------------------------------------------
// f32 -> bf16 elementwise convert (vectorized: float4 in, ushort4 out)
__global__ void convert_f32_bf16(const float* __restrict__ in, u16* __restrict__ out, int n4) {
    int i = blockIdx.x * blockDim.x + threadIdx.x;
    if (i < n4) {
        float4 v = *(const float4*)&in[(size_t)i * 4];
        u16x4 o;
        o.x = f2bf(v.x); o.y = f2bf(v.y); o.z = f2bf(v.z); o.w = f2bf(v.w);
        *(u16x4*)&out[(size_t)i * 4] = o;
    }
}

// ---------------------------------------------------------------------------
// out[c][r] = bf16(in[r][c]); in is [R][C] f32 row-major. 64x64 tiles.
__global__ void transpose_convert(const float* __restrict__ in, u16* __restrict__ out, int R, int C) {
    __shared__ float tl[64][65];
    const int rb = blockIdx.x, cb = blockIdx.y;
    const int tid = threadIdx.x;
    for (int it = 0; it < 4; ++it) {
        int lin = (tid + it * 256) * 4;
        int r = lin >> 6, c = lin & 63;
        float4 v = *(const float4*)&in[(size_t)(rb * 64 + r) * C + cb * 64 + c];
        tl[r][c + 0] = v.x; tl[r][c + 1] = v.y; tl[r][c + 2] = v.z; tl[r][c + 3] = v.w;
    }
    __syncthreads();
    for (int it = 0; it < 4; ++it) {
        int lin = (tid + it * 256) * 4;
        int oc = lin >> 6, orr = lin & 63;   // out-row (c of in), out-col (r of in)
        u16x4 o;
        o.x = f2bf(tl[orr + 0][oc]);
        o.y = f2bf(tl[orr + 1][oc]);
        o.z = f2bf(tl[orr + 2][oc]);
        o.w = f2bf(tl[orr + 3][oc]);
        *(u16x4*)&out[(size_t)(cb * 64 + oc) * R + rb * 64 + orr] = o;
    }
}

// ---------------------------------------------------------------------------
// per (b,h): v_buf [2048][64] -> vt_buf [64][2048]   (bf16)
__global__ void transpose_v(const u16* __restrict__ vbuf, u16* __restrict__ vtb) {
    __shared__ u16 tl[64][65];
    const int nb = blockIdx.x, bh = blockIdx.y;
    const int tid = threadIdx.x;
    for (int it = 0; it < 2; ++it) {
        int lin = (tid + it * 256) * 8;
        int nl = lin >> 6, dh = lin & 63;
        u16x8 v = *(const u16x8*)&vbuf[((size_t)bh * 2048 + nb * 64 + nl) * 64 + dh];
#pragma unroll
        for (int j = 0; j < 8; ++j) tl[dh + j][nl] = v[j];
    }
    __syncthreads();
    for (int it = 0; it < 2; ++it) {
        int lin = (tid + it * 256) * 8;
        int dh = lin >> 6, nl = lin & 63;
        u16x8 o;
#pragma unroll
        for (int j = 0; j < 8; ++j) o[j] = tl[dh][nl + j];
        *(u16x8*)&vtb[((size_t)bh * 64 + dh) * 2048 + nb * 64 + nl] = o;
    }
}

// ---------------------------------------------------------------------------
// C = A[M][K] @ Bt[N][K]^T + bias.  128x128 tile, BK=32, 4 waves (2x2), each 64x64.
// mode 0: scatter bf16 into q/k/v buffers [b,h][n][64]   (N==3072)
// mode 1: f32 out[M][N]                                   (N==1024)
__global__ __launch_bounds__(256) void gemm_bt(
    const u16* __restrict__ A, const u16* __restrict__ Bt, const float* __restrict__ bias,
    int M, int N, int K, int mode,
    u16* __restrict__ qb, u16* __restrict__ kb, u16* __restrict__ vb, float* __restrict__ outf) {
    __shared__ u16 Al[128 * 32];
    __shared__ u16 Bl[128 * 32];
    const int bm = blockIdx.x, bn = blockIdx.y;
    const int tid = threadIdx.x, wid = tid >> 6, lane = tid & 63;
    const int wr = wid >> 1, wc = wid & 1;
    const int l15 = lane & 15, lhi = lane >> 4;

    f32x4 acc[4][4];
#pragma unroll
    for (int i = 0; i < 4; ++i)
#pragma unroll
        for (int j = 0; j < 4; ++j) acc[i][j] = (f32x4){0.f, 0.f, 0.f, 0.f};

    for (int k0 = 0; k0 < K; k0 += 32) {
        __syncthreads();
#pragma unroll
        for (int s = 0; s < 2; ++s) {
            int lin0 = (wid * 2 + s) * 1024;           // byte offset in 8KB tile
            int off = lin0 + lane * 16;
            int row = off >> 6, colb = off & 63;       // 64B per row (32 bf16)
            const u16* ga = A + (size_t)(bm * 128 + row) * K + k0 + (colb >> 1);
            gload16(ga, (char*)Al + lin0);
            const u16* gb = Bt + (size_t)(bn * 128 + row) * K + k0 + (colb >> 1);
            gload16(gb, (char*)Bl + lin0);
        }
        __syncthreads();
        bf16x8 af[4], bf[4];
#pragma unroll
        for (int mt = 0; mt < 4; ++mt)
            af[mt] = *(const bf16x8*)&Al[(wr * 64 + mt * 16 + l15) * 32 + lhi * 8];
#pragma unroll
        for (int nt = 0; nt < 4; ++nt)
            bf[nt] = *(const bf16x8*)&Bl[(wc * 64 + nt * 16 + l15) * 32 + lhi * 8];
#pragma unroll
        for (int mt = 0; mt < 4; ++mt)
#pragma unroll
            for (int nt = 0; nt < 4; ++nt)
                acc[mt][nt] = MFMA16(af[mt], bf[nt], acc[mt][nt]);
    }

#pragma unroll
    for (int mt = 0; mt < 4; ++mt)
#pragma unroll
        for (int nt = 0; nt < 4; ++nt)
#pragma unroll
            for (int v = 0; v < 4; ++v) {
                int rg = bm * 128 + wr * 64 + mt * 16 + lhi * 4 + v;
                int cg = bn * 128 + wc * 64 + nt * 16 + l15;
                float val = acc[mt][nt][v] + bias[cg];
                if (mode == 0) {
                    int which = cg >> 10, rem = cg & 1023;
                    int hh = rem >> 6, dh = rem & 63;
                    int bb = rg >> 11, n = rg & 2047;
                    size_t idx = (((size_t)bb * 16 + hh) * 2048 + n) * 64 + dh;
                    u16 bv = f2bf(val);
                    if (which == 0) qb[idx] = bv;
                    else if (which == 1) kb[idx] = bv;
                    else vb[idx] = bv;
                } else {
                    outf[(size_t)rg * N + cg] = val;
                }
            }
}

// ---------------------------------------------------------------------------
// Flash attention fwd, causal. Block = (b,h,q-tile 64). 4 waves x 16 q-rows.
// KVBLK=64. K in [n][64], V pre-transposed Vt[64][n]. Output obuf[b*2048+n][h*64+dh] bf16.
__global__ __launch_bounds__(256) void attn_kernel(
    const u16* __restrict__ qbuf, const u16* __restrict__ kbuf,
    const u16* __restrict__ vtb, u16* __restrict__ obuf) {
    __shared__ u16 Kl[64 * 64];
    __shared__ u16 Vtl[64 * 64];
    __shared__ u16 Pl[4 * 16 * 64];
    const int qt = blockIdx.x, bh = blockIdx.y;
    const int b = bh >> 4, h = bh & 15;
    const int tid = threadIdx.x, wid = tid >> 6, lane = tid & 63;
    const int l15 = lane & 15, lhi = lane >> 4;
    const int qbase = qt * 64;
    const int qg = qbase + wid * 16 + lhi * 4;  // + v

    bf16x8 qf[2];
    {
        const size_t qrow = (size_t)bh * 2048 + qbase + wid * 16 + l15;
        qf[0] = *(const bf16x8*)&qbuf[qrow * 64 + lhi * 8];
        qf[1] = *(const bf16x8*)&qbuf[qrow * 64 + 32 + lhi * 8];
    }

    float m_s[4], l_s[4];
    f32x4 oa[4];
#pragma unroll
    for (int v = 0; v < 4; ++v) { m_s[v] = -__builtin_inff(); l_s[v] = 0.f; }
#pragma unroll
    for (int d = 0; d < 4; ++d) oa[d] = (f32x4){0.f, 0.f, 0.f, 0.f};

    for (int t = 0; t <= qt; ++t) {
        const int kbase = t * 64;
        __syncthreads();
#pragma unroll
        for (int s = 0; s < 2; ++s) {
            int lin0 = (wid * 2 + s) * 1024;
            int off = lin0 + lane * 16;
            int row = off >> 7, colb = off & 127;   // 128B per row (64 bf16)
            const u16* gk = kbuf + ((size_t)bh * 2048 + kbase + row) * 64 + (colb >> 1);
            gload16(gk, (char*)Kl + lin0);
            const u16* gv = vtb + ((size_t)bh * 64 + row) * 2048 + kbase + (colb >> 1);
            gload16(gv, (char*)Vtl + lin0);
        }
        __syncthreads();

        // S = Q K^T  (C-layout: row=(lhi*4+v)=q_local, col=l15=k_local within nkb)
        f32x4 s[4];
#pragma unroll
        for (int nkb = 0; nkb < 4; ++nkb) {
            f32x4 a = (f32x4){0.f, 0.f, 0.f, 0.f};
            bf16x8 kf0 = *(const bf16x8*)&Kl[(nkb * 16 + l15) * 64 + lhi * 8];
            bf16x8 kf1 = *(const bf16x8*)&Kl[(nkb * 16 + l15) * 64 + 32 + lhi * 8];
            a = MFMA16(qf[0], kf0, a);
            a = MFMA16(qf[1], kf1, a);
            s[nkb] = a;
        }
        const float scale = 0.125f;  // 1/sqrt(64)
        const bool lastTile = (t == qt);
#pragma unroll
        for (int nkb = 0; nkb < 4; ++nkb)
#pragma unroll
            for (int v = 0; v < 4; ++v) {
                float x = s[nkb][v] * scale;
                if (lastTile) {
                    int kg = kbase + nkb * 16 + l15;
                    if (kg > qg + v) x = -__builtin_inff();
                }
                s[nkb][v] = x;
            }
        // online softmax
        float fvec[4], rsum[4];
#pragma unroll
        for (int v = 0; v < 4; ++v) {
            float m0 = fmaxf(fmaxf(s[0][v], s[1][v]), fmaxf(s[2][v], s[3][v]));
#pragma unroll
            for (int d = 1; d < 16; d <<= 1) m0 = fmaxf(m0, __shfl_xor(m0, d, 64));
            float nm = fmaxf(m_s[v], m0);
            fvec[v] = expf(m_s[v] - nm);
            m_s[v] = nm;
            rsum[v] = 0.f;
        }
#pragma unroll
        for (int nkb = 0; nkb < 4; ++nkb)
#pragma unroll
            for (int v = 0; v < 4; ++v) {
                float p = expf(s[nkb][v] - m_s[v]);
                rsum[v] += p;
                Pl[wid * 1024 + (lhi * 4 + v) * 64 + nkb * 16 + l15] = f2bf(p);
            }
#pragma unroll
        for (int v = 0; v < 4; ++v) {
#pragma unroll
            for (int d = 1; d < 16; d <<= 1) rsum[v] += __shfl_xor(rsum[v], d, 64);
            l_s[v] = l_s[v] * fvec[v] + rsum[v];
        }
#pragma unroll
        for (int dhb = 0; dhb < 4; ++dhb)
#pragma unroll
            for (int v = 0; v < 4; ++v) oa[dhb][v] *= fvec[v];
        // O += P V   (A-frag: P[q=l15][nk], B-frag: V[nk][dh=l15] = Vtl[dh][nk])
#pragma unroll
        for (int ks = 0; ks < 2; ++ks) {
            bf16x8 pa = *(const bf16x8*)&Pl[wid * 1024 + l15 * 64 + ks * 32 + lhi * 8];
#pragma unroll
            for (int dhb = 0; dhb < 4; ++dhb) {
                bf16x8 vf = *(const bf16x8*)&Vtl[(dhb * 16 + l15) * 64 + ks * 32 + lhi * 8];
                oa[dhb] = MFMA16(pa, vf, oa[dhb]);
            }
        }
    }
    // epilogue: O /= l, write [b*2048+n][h*64+dh]
#pragma unroll
    for (int dhb = 0; dhb < 4; ++dhb)
#pragma unroll
        for (int v = 0; v < 4; ++v) {
            float o = oa[dhb][v] / l_s[v];
            int qrow = qg + v;
            obuf[((size_t)b * 2048 + qrow) * 1024 + h * 64 + dhb * 16 + l15] = f2bf(o);
        }
}

// ---------------------------------------------------------------------------
extern "C" void kernel_launch(void* const* d_in, const int* in_sizes, int n_in,
                              void* d_out, int out_size, void* d_ws, size_t ws_size,
                              hipStream_t stream) {
    const float* inp   = (const float*)d_in[0];   // [4,2048,1024]
    const float* W_qkv = (const float*)d_in[1];   // [1024,3072]
    const float* b_qkv = (const float*)d_in[2];   // [3072]
    const float* W_out = (const float*)d_in[3];   // [1024,1024]
    const float* b_out = (const float*)d_in[4];   // [1024]
    float* out = (float*)d_out;                   // [4,2048,1024] f32

    // workspace carve-up (bf16 elements)
    u16* xb   = (u16*)d_ws;          // 8192x1024
    u16* wqt  = xb + 8388608;        // 3072x1024
    u16* wot  = wqt + 3145728;       // 1024x1024
    u16* qbuf = wot + 1048576;       // [64][2048][64]
    u16* kbuf = qbuf + 8388608;
    u16* vbuf = kbuf + 8388608;
    u16* vtb  = vbuf + 8388608;      // [64][64][2048]
    u16* obuf = vtb + 8388608;       // 8192x1024

    // 1. convert input to bf16
    convert_f32_bf16<<<8192, 256, 0, stream>>>(inp, xb, 2097152);
    // 2. transpose+convert weights
    transpose_convert<<<dim3(16, 48), 256, 0, stream>>>(W_qkv, wqt, 1024, 3072);
    transpose_convert<<<dim3(16, 16), 256, 0, stream>>>(W_out, wot, 1024, 1024);
    // 3. QKV projection
    gemm_bt<<<dim3(64, 24), 256, 0, stream>>>(xb, wqt, b_qkv, 8192, 3072, 1024, 0,
                                              qbuf, kbuf, vbuf, nullptr);
    // 4. transpose V per head
    transpose_v<<<dim3(32, 64), 256, 0, stream>>>(vbuf, vtb);
    // 5. attention
    attn_kernel<<<dim3(32, 64), 256, 0, stream>>>(qbuf, kbuf, vtb, obuf);
    // 6. output projection
    gemm_bt<<<dim3(64, 8), 256, 0, stream>>>(obuf, wot, b_out, 8192, 1024, 1024, 1,
                                             nullptr, nullptr, nullptr, out);
}

// Round 2
// 284.405 us; speedup vs baseline: 1.5619x; 1.5619x over previous
//
#include <hip/hip_runtime.h>
#include <hip/hip_bf16.h>

typedef unsigned short u16;
typedef __attribute__((ext_vector_type(4))) unsigned short u16x4;
typedef __attribute__((ext_vector_type(8))) unsigned short u16x8;
typedef __attribute__((ext_vector_type(8))) __bf16 bf16x8;
typedef __attribute__((ext_vector_type(4))) float f32x4;

typedef __attribute__((address_space(1))) void as1v;
typedef __attribute__((address_space(3))) void as3v;

#define MFMA16(a, b, c) __builtin_amdgcn_mfma_f32_16x16x32_bf16(a, b, c, 0, 0, 0)

__device__ __forceinline__ u16 f2bf(float f) {
    unsigned u = __builtin_bit_cast(unsigned, f);
    u += 0x7fffu + ((u >> 16) & 1u);
    return (u16)(u >> 16);
}

__device__ __forceinline__ void gload16(const void* g, void* l) {
    __builtin_amdgcn_global_load_lds((as1v*)g, (as3v*)l, 16, 0, 0);
}

// ---------------------------------------------------------------------------
__global__ void convert_f32_bf16(const float* __restrict__ in, u16* __restrict__ out, int n4) {
    int i = blockIdx.x * blockDim.x + threadIdx.x;
    if (i < n4) {
        float4 v = *(const float4*)&in[(size_t)i * 4];
        u16x4 o;
        o.x = f2bf(v.x); o.y = f2bf(v.y); o.z = f2bf(v.z); o.w = f2bf(v.w);
        *(u16x4*)&out[(size_t)i * 4] = o;
    }
}

// ---------------------------------------------------------------------------
__global__ void transpose_convert(const float* __restrict__ in, u16* __restrict__ out, int R, int C) {
    __shared__ float tl[64][65];
    const int rb = blockIdx.x, cb = blockIdx.y;
    const int tid = threadIdx.x;
    for (int it = 0; it < 4; ++it) {
        int lin = (tid + it * 256) * 4;
        int r = lin >> 6, c = lin & 63;
        float4 v = *(const float4*)&in[(size_t)(rb * 64 + r) * C + cb * 64 + c];
        tl[r][c + 0] = v.x; tl[r][c + 1] = v.y; tl[r][c + 2] = v.z; tl[r][c + 3] = v.w;
    }
    __syncthreads();
    for (int it = 0; it < 4; ++it) {
        int lin = (tid + it * 256) * 4;
        int oc = lin >> 6, orr = lin & 63;
        u16x4 o;
        o.x = f2bf(tl[orr + 0][oc]);
        o.y = f2bf(tl[orr + 1][oc]);
        o.z = f2bf(tl[orr + 2][oc]);
        o.w = f2bf(tl[orr + 3][oc]);
        *(u16x4*)&out[(size_t)(cb * 64 + oc) * R + rb * 64 + orr] = o;
    }
}

// ---------------------------------------------------------------------------
__global__ void transpose_v(const u16* __restrict__ vbuf, u16* __restrict__ vtb) {
    __shared__ u16 tl[64][65];
    const int nb = blockIdx.x, bh = blockIdx.y;
    const int tid = threadIdx.x;
    for (int it = 0; it < 2; ++it) {
        int lin = (tid + it * 256) * 8;
        int nl = lin >> 6, dh = lin & 63;
        u16x8 v = *(const u16x8*)&vbuf[((size_t)bh * 2048 + nb * 64 + nl) * 64 + dh];
#pragma unroll
        for (int j = 0; j < 8; ++j) tl[dh + j][nl] = v[j];
    }
    __syncthreads();
    for (int it = 0; it < 2; ++it) {
        int lin = (tid + it * 256) * 8;
        int dh = lin >> 6, nl = lin & 63;
        u16x8 o;
#pragma unroll
        for (int j = 0; j < 8; ++j) o[j] = tl[dh][nl + j];
        *(u16x8*)&vtb[((size_t)bh * 64 + dh) * 2048 + nb * 64 + nl] = o;
    }
}

// ---------------------------------------------------------------------------
// C = A[M][K] @ Bt[N][K]^T + bias.  128x128 tile, BK=32, 4 waves (2x2), each 64x64.
__global__ __launch_bounds__(256) void gemm_bt(
    const u16* __restrict__ A, const u16* __restrict__ Bt, const float* __restrict__ bias,
    int M, int N, int K, int mode,
    u16* __restrict__ qb, u16* __restrict__ kb, u16* __restrict__ vb, float* __restrict__ outf) {
    __shared__ u16 Al[128 * 32];
    __shared__ u16 Bl[128 * 32];
    const int bm = blockIdx.x, bn = blockIdx.y;
    const int tid = threadIdx.x, wid = tid >> 6, lane = tid & 63;
    const int wr = wid >> 1, wc = wid & 1;
    const int l15 = lane & 15, lhi = lane >> 4;

    f32x4 acc[4][4];
#pragma unroll
    for (int i = 0; i < 4; ++i)
#pragma unroll
        for (int j = 0; j < 4; ++j) acc[i][j] = (f32x4){0.f, 0.f, 0.f, 0.f};

    for (int k0 = 0; k0 < K; k0 += 32) {
        __syncthreads();
#pragma unroll
        for (int s = 0; s < 2; ++s) {
            int lin0 = (wid * 2 + s) * 1024;
            int off = lin0 + lane * 16;
            int row = off >> 6, colb = off & 63;
            const u16* ga = A + (size_t)(bm * 128 + row) * K + k0 + (colb >> 1);
            gload16(ga, (char*)Al + lin0);
            const u16* gb = Bt + (size_t)(bn * 128 + row) * K + k0 + (colb >> 1);
            gload16(gb, (char*)Bl + lin0);
        }
        __syncthreads();
        bf16x8 af[4], bfr[4];
#pragma unroll
        for (int mt = 0; mt < 4; ++mt)
            af[mt] = *(const bf16x8*)&Al[(wr * 64 + mt * 16 + l15) * 32 + lhi * 8];
#pragma unroll
        for (int nt = 0; nt < 4; ++nt)
            bfr[nt] = *(const bf16x8*)&Bl[(wc * 64 + nt * 16 + l15) * 32 + lhi * 8];
#pragma unroll
        for (int mt = 0; mt < 4; ++mt)
#pragma unroll
            for (int nt = 0; nt < 4; ++nt)
                acc[mt][nt] = MFMA16(af[mt], bfr[nt], acc[mt][nt]);
    }

#pragma unroll
    for (int mt = 0; mt < 4; ++mt)
#pragma unroll
        for (int nt = 0; nt < 4; ++nt)
#pragma unroll
            for (int v = 0; v < 4; ++v) {
                int rg = bm * 128 + wr * 64 + mt * 16 + lhi * 4 + v;
                int cg = bn * 128 + wc * 64 + nt * 16 + l15;
                float val = acc[mt][nt][v] + bias[cg];
                if (mode == 0) {
                    int which = cg >> 10, rem = cg & 1023;
                    int hh = rem >> 6, dh = rem & 63;
                    int bb = rg >> 11, n = rg & 2047;
                    size_t idx = (((size_t)bb * 16 + hh) * 2048 + n) * 64 + dh;
                    u16 bv = f2bf(val);
                    if (which == 0) qb[idx] = bv;
                    else if (which == 1) kb[idx] = bv;
                    else vb[idx] = bv;
                } else {
                    outf[(size_t)rg * N + cg] = val;
                }
            }
}

// ---------------------------------------------------------------------------
// Flash attention fwd, causal, paired q-tiles for load balance.
// Block (qi, bh): handles q-tiles ta=qi and tb=31-qi (shared K/V staging,
// exactly 33 tile-computes per block). 4 waves x 16 q-rows per tile.
// K/V LDS XOR-swizzled (row&7)<<4 bytes; P swizzled ((q>>1)&7)<<3 elems.
// Double-buffered K/V: one barrier per tile, stage t+1 issued before compute t.
__global__ __launch_bounds__(256) void attn_kernel(
    const u16* __restrict__ qbuf, const u16* __restrict__ kbuf,
    const u16* __restrict__ vtb, u16* __restrict__ obuf) {
    __shared__ u16 Kl[2][64 * 64];
    __shared__ u16 Vtl[2][64 * 64];
    __shared__ u16 Pl[4 * 16 * 64];
    const int qi = blockIdx.x, bh = blockIdx.y;
    const int b = bh >> 4, h = bh & 15;
    const int tid = threadIdx.x, wid = tid >> 6, lane = tid & 63;
    const int l15 = lane & 15, lhi = lane >> 4;
    const int ta = qi, tb = 31 - qi;
    const float SC = 0.125f * 1.44269504088896340736f;  // (1/sqrt(64))*log2(e)

    bf16x8 qfA[2], qfB[2];
    {
        size_t qrA = (size_t)bh * 2048 + ta * 64 + wid * 16 + l15;
        qfA[0] = *(const bf16x8*)&qbuf[qrA * 64 + lhi * 8];
        qfA[1] = *(const bf16x8*)&qbuf[qrA * 64 + 32 + lhi * 8];
        size_t qrB = (size_t)bh * 2048 + tb * 64 + wid * 16 + l15;
        qfB[0] = *(const bf16x8*)&qbuf[qrB * 64 + lhi * 8];
        qfB[1] = *(const bf16x8*)&qbuf[qrB * 64 + 32 + lhi * 8];
    }

    float mA[4], lA[4], mB[4], lB[4];
    f32x4 oA[4], oB[4];
#pragma unroll
    for (int v = 0; v < 4; ++v) {
        mA[v] = mB[v] = -__builtin_inff();
        lA[v] = lB[v] = 0.f;
    }
#pragma unroll
    for (int d = 0; d < 4; ++d) { oA[d] = (f32x4){0.f,0.f,0.f,0.f}; oB[d] = (f32x4){0.f,0.f,0.f,0.f}; }

    // staging constants: segment sg covers 8 rows of 128B; lane slot = sg*1024 + lane*16
    // linear LDS (row = sg*8 + lane>>3, colb = (lane&7)*16); source col pre-swizzled.
    const int srow = lane >> 3;                       // row&7 within segment
    const int scolb = ((lane & 7) * 16) ^ (srow << 4); // swizzled source byte col

    auto stage = [&](int buf, int t) {
        const int kbase = t * 64;
#pragma unroll
        for (int s = 0; s < 2; ++s) {
            int sg = wid * 2 + s;
            int row = sg * 8 + srow;
            const u16* gk = kbuf + ((size_t)bh * 2048 + kbase + row) * 64 + (scolb >> 1);
            gload16(gk, (char*)Kl[buf] + sg * 1024);
            const u16* gv = vtb + ((size_t)bh * 64 + row) * 2048 + kbase + (scolb >> 1);
            gload16(gv, (char*)Vtl[buf] + sg * 1024);
        }
    };

    auto computeTile = [&](int bufc, int t, int tile, const bf16x8* qf,
                           float* m_s, float* l_s, f32x4* oa) {
        const char* Kb = (const char*)Kl[bufc];
        const char* Vb = (const char*)Vtl[bufc];
        f32x4 s[4];
#pragma unroll
        for (int nkb = 0; nkb < 4; ++nkb) {
            int row = nkb * 16 + l15;
            int sw = (row & 7) << 4;
            bf16x8 kf0 = *(const bf16x8*)(Kb + row * 128 + ((lhi * 16) ^ sw));
            bf16x8 kf1 = *(const bf16x8*)(Kb + row * 128 + ((64 + lhi * 16) ^ sw));
            f32x4 a = (f32x4){0.f, 0.f, 0.f, 0.f};
            a = MFMA16(qf[0], kf0, a);
            a = MFMA16(qf[1], kf1, a);
            s[nkb] = a;
        }
        const bool diag = (t == tile);
        const int qg = tile * 64 + wid * 16 + lhi * 4;
#pragma unroll
        for (int nkb = 0; nkb < 4; ++nkb)
#pragma unroll
            for (int v = 0; v < 4; ++v) {
                float x = s[nkb][v] * SC;
                if (diag) {
                    int kg = t * 64 + nkb * 16 + l15;
                    if (kg > qg + v) x = -__builtin_inff();
                }
                s[nkb][v] = x;
            }
        float fvec[4], rsum[4];
#pragma unroll
        for (int v = 0; v < 4; ++v) {
            float m0 = fmaxf(fmaxf(s[0][v], s[1][v]), fmaxf(s[2][v], s[3][v]));
#pragma unroll
            for (int d = 1; d < 16; d <<= 1) m0 = fmaxf(m0, __shfl_xor(m0, d, 64));
            float nm = fmaxf(m_s[v], m0);
            fvec[v] = exp2f(m_s[v] - nm);
            m_s[v] = nm;
            rsum[v] = 0.f;
        }
#pragma unroll
        for (int nkb = 0; nkb < 4; ++nkb)
#pragma unroll
            for (int v = 0; v < 4; ++v) {
                float p = exp2f(s[nkb][v] - m_s[v]);
                rsum[v] += p;
                int q = lhi * 4 + v, k = nkb * 16 + l15;
                Pl[wid * 1024 + q * 64 + (k ^ ((q >> 1) << 3))] = f2bf(p);
            }
#pragma unroll
        for (int v = 0; v < 4; ++v) {
#pragma unroll
            for (int d = 1; d < 16; d <<= 1) rsum[v] += __shfl_xor(rsum[v], d, 64);
            l_s[v] = l_s[v] * fvec[v] + rsum[v];
        }
#pragma unroll
        for (int dhb = 0; dhb < 4; ++dhb)
#pragma unroll
            for (int v = 0; v < 4; ++v) oa[dhb][v] *= fvec[v];
#pragma unroll
        for (int ks = 0; ks < 2; ++ks) {
            bf16x8 pa = *(const bf16x8*)&Pl[wid * 1024 + l15 * 64 +
                                            (((ks * 32 + lhi * 8)) ^ ((l15 >> 1) << 3))];
#pragma unroll
            for (int dhb = 0; dhb < 4; ++dhb) {
                int vrow = dhb * 16 + l15;
                bf16x8 vf = *(const bf16x8*)(Vb + vrow * 128 +
                                             ((ks * 64 + lhi * 16) ^ ((vrow & 7) << 4)));
                oa[dhb] = MFMA16(pa, vf, oa[dhb]);
            }
        }
    };

    stage(0, 0);
    int cur = 0;
    for (int t = 0; t <= tb; ++t) {
        __syncthreads();
        if (t < tb) stage(cur ^ 1, t + 1);
        computeTile(cur, t, tb, qfB, mB, lB, oB);
        if (t <= ta) computeTile(cur, t, ta, qfA, mA, lA, oA);
        cur ^= 1;
    }

    auto epilogue = [&](int tile, const float* l_s, const f32x4* oa) {
        const int qg = tile * 64 + wid * 16 + lhi * 4;
#pragma unroll
        for (int v = 0; v < 4; ++v) {
            float rl = 1.0f / l_s[v];
            int qrow = qg + v;
#pragma unroll
            for (int dhb = 0; dhb < 4; ++dhb)
                obuf[((size_t)b * 2048 + qrow) * 1024 + h * 64 + dhb * 16 + l15] =
                    f2bf(oa[dhb][v] * rl);
        }
    };
    epilogue(ta, lA, oA);
    epilogue(tb, lB, oB);
}

// ---------------------------------------------------------------------------
extern "C" void kernel_launch(void* const* d_in, const int* in_sizes, int n_in,
                              void* d_out, int out_size, void* d_ws, size_t ws_size,
                              hipStream_t stream) {
    const float* inp   = (const float*)d_in[0];   // [4,2048,1024]
    const float* W_qkv = (const float*)d_in[1];   // [1024,3072]
    const float* b_qkv = (const float*)d_in[2];   // [3072]
    const float* W_out = (const float*)d_in[3];   // [1024,1024]
    const float* b_out = (const float*)d_in[4];   // [1024]
    float* out = (float*)d_out;                   // [4,2048,1024] f32

    u16* xb   = (u16*)d_ws;          // 8192x1024
    u16* wqt  = xb + 8388608;        // 3072x1024
    u16* wot  = wqt + 3145728;       // 1024x1024
    u16* qbuf = wot + 1048576;       // [64][2048][64]
    u16* kbuf = qbuf + 8388608;
    u16* vbuf = kbuf + 8388608;
    u16* vtb  = vbuf + 8388608;      // [64][64][2048]
    u16* obuf = vtb + 8388608;       // 8192x1024

    convert_f32_bf16<<<8192, 256, 0, stream>>>(inp, xb, 2097152);
    transpose_convert<<<dim3(16, 48), 256, 0, stream>>>(W_qkv, wqt, 1024, 3072);
    transpose_convert<<<dim3(16, 16), 256, 0, stream>>>(W_out, wot, 1024, 1024);
    gemm_bt<<<dim3(64, 24), 256, 0, stream>>>(xb, wqt, b_qkv, 8192, 3072, 1024, 0,
                                              qbuf, kbuf, vbuf, nullptr);
    transpose_v<<<dim3(32, 64), 256, 0, stream>>>(vbuf, vtb);
    attn_kernel<<<dim3(16, 64), 256, 0, stream>>>(qbuf, kbuf, vtb, obuf);
    gemm_bt<<<dim3(64, 8), 256, 0, stream>>>(obuf, wot, b_out, 8192, 1024, 1024, 1,
                                             nullptr, nullptr, nullptr, out);
}

// Round 5
// 219.097 us; speedup vs baseline: 2.0275x; 1.2981x over previous
//
#include <hip/hip_runtime.h>
#include <hip/hip_bf16.h>

typedef unsigned short u16;
typedef unsigned u32;
typedef __attribute__((ext_vector_type(4))) unsigned short u16x4;
typedef __attribute__((ext_vector_type(8))) unsigned short u16x8;
typedef __attribute__((ext_vector_type(4))) unsigned u32x4;
typedef __attribute__((ext_vector_type(8))) __bf16 bf16x8;
typedef __attribute__((ext_vector_type(4))) float f32x4;

typedef __attribute__((address_space(1))) void as1v;
typedef __attribute__((address_space(3))) void as3v;

#define MFMA16(a, b, c) __builtin_amdgcn_mfma_f32_16x16x32_bf16(a, b, c, 0, 0, 0)

__device__ __forceinline__ u16 f2bf(float f) {
    unsigned u = __builtin_bit_cast(unsigned, f);
    u += 0x7fffu + ((u >> 16) & 1u);
    return (u16)(u >> 16);
}

__device__ __forceinline__ u32 pkbf(float lo, float hi) {
    u32 r;
    asm("v_cvt_pk_bf16_f32 %0, %1, %2" : "=v"(r) : "v"(lo), "v"(hi));
    return r;
}

__device__ __forceinline__ void gload16(const void* g, void* l) {
    __builtin_amdgcn_global_load_lds((as1v*)g, (as3v*)l, 16, 0, 0);
}

// ---------------------------------------------------------------------------
__global__ void convert_f32_bf16(const float* __restrict__ in, u16* __restrict__ out, int n4) {
    int i = blockIdx.x * blockDim.x + threadIdx.x;
    if (i < n4) {
        float4 v = *(const float4*)&in[(size_t)i * 4];
        u16x4 o;
        o.x = f2bf(v.x); o.y = f2bf(v.y); o.z = f2bf(v.z); o.w = f2bf(v.w);
        *(u16x4*)&out[(size_t)i * 4] = o;
    }
}

// ---------------------------------------------------------------------------
__global__ void transpose_convert(const float* __restrict__ in, u16* __restrict__ out, int R, int C) {
    __shared__ float tl[64][65];
    const int rb = blockIdx.x, cb = blockIdx.y;
    const int tid = threadIdx.x;
    for (int it = 0; it < 4; ++it) {
        int lin = (tid + it * 256) * 4;
        int r = lin >> 6, c = lin & 63;
        float4 v = *(const float4*)&in[(size_t)(rb * 64 + r) * C + cb * 64 + c];
        tl[r][c + 0] = v.x; tl[r][c + 1] = v.y; tl[r][c + 2] = v.z; tl[r][c + 3] = v.w;
    }
    __syncthreads();
    for (int it = 0; it < 4; ++it) {
        int lin = (tid + it * 256) * 4;
        int oc = lin >> 6, orr = lin & 63;
        u16x4 o;
        o.x = f2bf(tl[orr + 0][oc]);
        o.y = f2bf(tl[orr + 1][oc]);
        o.z = f2bf(tl[orr + 2][oc]);
        o.w = f2bf(tl[orr + 3][oc]);
        *(u16x4*)&out[(size_t)(cb * 64 + oc) * R + rb * 64 + orr] = o;
    }
}

// ---------------------------------------------------------------------------
__global__ void transpose_v(const u16* __restrict__ vbuf, u16* __restrict__ vtb) {
    __shared__ u16 tl[64][65];
    const int nb = blockIdx.x, bh = blockIdx.y;
    const int tid = threadIdx.x;
    for (int it = 0; it < 2; ++it) {
        int lin = (tid + it * 256) * 8;
        int nl = lin >> 6, dh = lin & 63;
        u16x8 v = *(const u16x8*)&vbuf[((size_t)bh * 2048 + nb * 64 + nl) * 64 + dh];
#pragma unroll
        for (int j = 0; j < 8; ++j) tl[dh + j][nl] = v[j];
    }
    __syncthreads();
    for (int it = 0; it < 2; ++it) {
        int lin = (tid + it * 256) * 8;
        int dh = lin >> 6, nl = lin & 63;
        u16x8 o;
#pragma unroll
        for (int j = 0; j < 8; ++j) o[j] = tl[dh][nl + j];
        *(u16x8*)&vtb[((size_t)bh * 64 + dh) * 2048 + nb * 64 + nl] = o;
    }
}

// ---------------------------------------------------------------------------
// C = A[M][K] @ Bt[N][K]^T + bias.  128x128 tile, BK=32, 4 waves (2x2), each 64x64.
// mode 0: scatter bf16 into q/k/v buffers; Q is pre-scaled by 0.125*log2(e).
__global__ __launch_bounds__(256) void gemm_bt(
    const u16* __restrict__ A, const u16* __restrict__ Bt, const float* __restrict__ bias,
    int M, int N, int K, int mode,
    u16* __restrict__ qb, u16* __restrict__ kb, u16* __restrict__ vb, float* __restrict__ outf) {
    __shared__ u16 Al[128 * 32];
    __shared__ u16 Bl[128 * 32];
    const int bm = blockIdx.x, bn = blockIdx.y;
    const int tid = threadIdx.x, wid = tid >> 6, lane = tid & 63;
    const int wr = wid >> 1, wc = wid & 1;
    const int l15 = lane & 15, lhi = lane >> 4;

    f32x4 acc[4][4];
#pragma unroll
    for (int i = 0; i < 4; ++i)
#pragma unroll
        for (int j = 0; j < 4; ++j) acc[i][j] = (f32x4){0.f, 0.f, 0.f, 0.f};

    for (int k0 = 0; k0 < K; k0 += 32) {
        __syncthreads();
#pragma unroll
        for (int s = 0; s < 2; ++s) {
            int lin0 = (wid * 2 + s) * 1024;
            int off = lin0 + lane * 16;
            int row = off >> 6, colb = off & 63;
            const u16* ga = A + (size_t)(bm * 128 + row) * K + k0 + (colb >> 1);
            gload16(ga, (char*)Al + lin0);
            const u16* gb = Bt + (size_t)(bn * 128 + row) * K + k0 + (colb >> 1);
            gload16(gb, (char*)Bl + lin0);
        }
        __syncthreads();
        bf16x8 af[4], bfr[4];
#pragma unroll
        for (int mt = 0; mt < 4; ++mt)
            af[mt] = *(const bf16x8*)&Al[(wr * 64 + mt * 16 + l15) * 32 + lhi * 8];
#pragma unroll
        for (int nt = 0; nt < 4; ++nt)
            bfr[nt] = *(const bf16x8*)&Bl[(wc * 64 + nt * 16 + l15) * 32 + lhi * 8];
#pragma unroll
        for (int mt = 0; mt < 4; ++mt)
#pragma unroll
            for (int nt = 0; nt < 4; ++nt)
                acc[mt][nt] = MFMA16(af[mt], bfr[nt], acc[mt][nt]);
    }

#pragma unroll
    for (int mt = 0; mt < 4; ++mt)
#pragma unroll
        for (int nt = 0; nt < 4; ++nt)
#pragma unroll
            for (int v = 0; v < 4; ++v) {
                int rg = bm * 128 + wr * 64 + mt * 16 + lhi * 4 + v;
                int cg = bn * 128 + wc * 64 + nt * 16 + l15;
                float val = acc[mt][nt][v] + bias[cg];
                if (mode == 0) {
                    int which = cg >> 10, rem = cg & 1023;
                    int hh = rem >> 6, dh = rem & 63;
                    int bb = rg >> 11, n = rg & 2047;
                    size_t idx = (((size_t)bb * 16 + hh) * 2048 + n) * 64 + dh;
                    if (which == 0) qb[idx] = f2bf(val * 0.18033688011112042f); // *0.125*log2e
                    else if (which == 1) kb[idx] = f2bf(val);
                    else vb[idx] = f2bf(val);
                } else {
                    outf[(size_t)rg * N + cg] = val;
                }
            }
}

// ---------------------------------------------------------------------------
// Flash attention fwd, causal — 16x16x32 swapped-operand structure (all MFMA
// facts verified by passing rounds 1-2: A/B same-slot pairing + m89/m91 C/D map).
//   S^T = mfma16(K, Q^T): D row = k-local = kb4*16 + lhi*4 + v, col = q = l15.
//   Softmax in-register: in-lane over 16 vals + shfl_xor(16) + shfl_xor(32).
//   P packed in NATURAL slot order; V A-frag loaded as two b64s at element
//   cols {ks*32+4*lhi, ks*32+16+4*lhi} so V's slot->k map equals P's
//   (correct for ANY hw slot map given same-slot A/B pairing).
//   O^T = mfma16(V^T, P^T): rows = dh, col = q; rescale is a lane scalar.
// Block: chunk pair (p, 31-p), 64 q each; wave = 16 q of each chunk.
// ntA = p+1, ntB = ntmax = 32-p (uniform across waves). Double-buffered
// XOR-swizzled K/V staging (identical to round-2-verified code).
__global__ __launch_bounds__(256, 2) void attn_kernel(
    const u16* __restrict__ qbuf, const u16* __restrict__ kbuf,
    const u16* __restrict__ vtb, u16* __restrict__ obuf) {
    __shared__ u16 Kl[2][64 * 64];
    __shared__ u16 Vl[2][64 * 64];
    const int p = blockIdx.x, bh = blockIdx.y;
    const int b = bh >> 4, h = bh & 15;
    const int tid = threadIdx.x, wid = tid >> 6, lane = tid & 63;
    const int l15 = lane & 15, lhi = lane >> 4;
    const int qA0 = p * 64 + wid * 16;
    const int qB0 = (31 - p) * 64 + wid * 16;
    const int ntA = p + 1;
    const int ntmax = 32 - p;   // == ntB for all waves

    // Q fragments: Q[q = q0+l15][d = dj*32 + lhi*8 .. +8]
    bf16x8 qfA[2], qfB[2];
    {
        const u16* qa = qbuf + ((size_t)bh * 2048 + qA0 + l15) * 64 + lhi * 8;
        const u16* qbp = qbuf + ((size_t)bh * 2048 + qB0 + l15) * 64 + lhi * 8;
        qfA[0] = *(const bf16x8*)(qa);
        qfA[1] = *(const bf16x8*)(qa + 32);
        qfB[0] = *(const bf16x8*)(qbp);
        qfB[1] = *(const bf16x8*)(qbp + 32);
    }

    float mA = -1e30f, lA = 0.f, mB = -1e30f, lB = 0.f;
    f32x4 oA[4], oB[4];
#pragma unroll
    for (int d = 0; d < 4; ++d) {
        oA[d] = (f32x4){0.f, 0.f, 0.f, 0.f};
        oB[d] = (f32x4){0.f, 0.f, 0.f, 0.f};
    }

    const int srow = lane >> 3;
    const int scolb = ((lane & 7) * 16) ^ (srow << 4);

    auto stage = [&](int buf, int t) {
        const int kbase = t * 64;
#pragma unroll
        for (int s = 0; s < 2; ++s) {
            int sg = wid * 2 + s;
            int row = sg * 8 + srow;
            const u16* gk = kbuf + ((size_t)bh * 2048 + kbase + row) * 64 + (scolb >> 1);
            gload16(gk, (char*)Kl[buf] + sg * 1024);
            const u16* gv = vtb + ((size_t)bh * 64 + row) * 2048 + kbase + (scolb >> 1);
            gload16(gv, (char*)Vl[buf] + sg * 1024);
        }
    };

    auto computeTile = [&](int bufc, int t, int q0, const bf16x8* qf,
                           float& m, float& l, f32x4* oa) {
        const char* Kb = (const char*)Kl[bufc];
        const char* Vb = (const char*)Vl[bufc];
        f32x4 s[4];
        __builtin_amdgcn_s_setprio(1);
#pragma unroll
        for (int kb4 = 0; kb4 < 4; ++kb4) {
            const int r = kb4 * 16 + l15;
            const int sw = (r & 7) << 4;
            const int rowb = r * 128;
            f32x4 a = (f32x4){0.f, 0.f, 0.f, 0.f};
            a = MFMA16(*(const bf16x8*)(Kb + rowb + ((lhi * 16) ^ sw)), qf[0], a);
            a = MFMA16(*(const bf16x8*)(Kb + rowb + ((64 + lhi * 16) ^ sw)), qf[1], a);
            s[kb4] = a;
        }
        __builtin_amdgcn_s_setprio(0);
        const int qg = q0 + l15;
        if (64 * t + 63 > q0) {
#pragma unroll
            for (int kb4 = 0; kb4 < 4; ++kb4)
#pragma unroll
                for (int v = 0; v < 4; ++v) {
                    int kg = 64 * t + kb4 * 16 + lhi * 4 + v;
                    if (kg > qg) s[kb4][v] = -1e30f;
                }
        }
        // row reduce: in-lane 16 + cross-lane (lanes l15+16*lhi share row q)
        float pm = fmaxf(fmaxf(fmaxf(s[0][0], s[0][1]), fmaxf(s[0][2], s[0][3])),
                         fmaxf(fmaxf(s[1][0], s[1][1]), fmaxf(s[1][2], s[1][3])));
        pm = fmaxf(pm, fmaxf(fmaxf(fmaxf(s[2][0], s[2][1]), fmaxf(s[2][2], s[2][3])),
                             fmaxf(fmaxf(s[3][0], s[3][1]), fmaxf(s[3][2], s[3][3]))));
        pm = fmaxf(pm, __shfl_xor(pm, 16, 64));
        pm = fmaxf(pm, __shfl_xor(pm, 32, 64));
        float nm = fmaxf(m, pm);
        float f = exp2f(m - nm);
        m = nm;
        float rs = 0.f;
#pragma unroll
        for (int kb4 = 0; kb4 < 4; ++kb4)
#pragma unroll
            for (int v = 0; v < 4; ++v) {
                float e = exp2f(s[kb4][v] - nm);
                s[kb4][v] = e;
                rs += e;
            }
        rs += __shfl_xor(rs, 16, 64);
        rs += __shfl_xor(rs, 32, 64);
        l = l * f + rs;
#pragma unroll
        for (int d = 0; d < 4; ++d)
#pragma unroll
            for (int v = 0; v < 4; ++v) oa[d][v] *= f;
        // P pack, natural slots: B-frag slot j (<4): s[2ks][j]; slot j>=4: s[2ks+1][j-4]
        u32 pw0[4], pw1[4];
        pw0[0] = pkbf(s[0][0], s[0][1]); pw0[1] = pkbf(s[0][2], s[0][3]);
        pw0[2] = pkbf(s[1][0], s[1][1]); pw0[3] = pkbf(s[1][2], s[1][3]);
        pw1[0] = pkbf(s[2][0], s[2][1]); pw1[1] = pkbf(s[2][2], s[2][3]);
        pw1[2] = pkbf(s[3][0], s[3][1]); pw1[3] = pkbf(s[3][2], s[3][3]);
        __builtin_amdgcn_s_setprio(1);
#pragma unroll
        for (int ks = 0; ks < 2; ++ks) {
            bf16x8 pb = __builtin_bit_cast(bf16x8,
                ks == 0 ? (u32x4){pw0[0], pw0[1], pw0[2], pw0[3]}
                        : (u32x4){pw1[0], pw1[1], pw1[2], pw1[3]});
#pragma unroll
            for (int dhb = 0; dhb < 4; ++dhb) {
                const int r = dhb * 16 + l15;
                const int sw = (r & 7) << 4;
                // V slots match P: elems {ks*32+4*lhi+0..3, ks*32+16+4*lhi+0..3}
                u16x4 v0 = *(const u16x4*)(Vb + r * 128 + ((ks * 64 + 8 * lhi) ^ sw));
                u16x4 v1 = *(const u16x4*)(Vb + r * 128 + ((ks * 64 + 32 + 8 * lhi) ^ sw));
                u16x8 vv = {v0[0], v0[1], v0[2], v0[3], v1[0], v1[1], v1[2], v1[3]};
                oa[dhb] = MFMA16(__builtin_bit_cast(bf16x8, vv), pb, oa[dhb]);
            }
        }
        __builtin_amdgcn_s_setprio(0);
    };

    stage(0, 0);
    int cur = 0;
    for (int t = 0; t < ntmax; ++t) {
        __syncthreads();
        if (t + 1 < ntmax) stage(cur ^ 1, t + 1);
        computeTile(cur, t, qB0, qfB, mB, lB, oB);
        if (t < ntA) computeTile(cur, t, qA0, qfA, mA, lA, oA);
        cur ^= 1;
    }

    // epilogue: q = q0+l15; dh = dhb*16 + lhi*4 + v
    auto epi = [&](int q0, float l, const f32x4* oa) {
        const float rl = 1.f / l;
        const int q = q0 + l15;
        const size_t rowoff = ((size_t)b * 2048 + q) * 1024 + h * 64;
#pragma unroll
        for (int dhb = 0; dhb < 4; ++dhb) {
            u16x4 w;
#pragma unroll
            for (int v = 0; v < 4; ++v) w[v] = f2bf(oa[dhb][v] * rl);
            *(u16x4*)&obuf[rowoff + dhb * 16 + lhi * 4] = w;
        }
    };
    epi(qA0, lA, oA);
    epi(qB0, lB, oB);
}

// ---------------------------------------------------------------------------
extern "C" void kernel_launch(void* const* d_in, const int* in_sizes, int n_in,
                              void* d_out, int out_size, void* d_ws, size_t ws_size,
                              hipStream_t stream) {
    const float* inp   = (const float*)d_in[0];   // [4,2048,1024]
    const float* W_qkv = (const float*)d_in[1];   // [1024,3072]
    const float* b_qkv = (const float*)d_in[2];   // [3072]
    const float* W_out = (const float*)d_in[3];   // [1024,1024]
    const float* b_out = (const float*)d_in[4];   // [1024]
    float* out = (float*)d_out;                   // [4,2048,1024] f32

    u16* xb   = (u16*)d_ws;          // 8192x1024
    u16* wqt  = xb + 8388608;        // 3072x1024
    u16* wot  = wqt + 3145728;       // 1024x1024
    u16* qbuf = wot + 1048576;       // [64][2048][64]
    u16* kbuf = qbuf + 8388608;
    u16* vbuf = kbuf + 8388608;
    u16* vtb  = vbuf + 8388608;      // [64][64][2048]
    u16* obuf = vtb + 8388608;       // 8192x1024

    convert_f32_bf16<<<8192, 256, 0, stream>>>(inp, xb, 2097152);
    transpose_convert<<<dim3(16, 48), 256, 0, stream>>>(W_qkv, wqt, 1024, 3072);
    transpose_convert<<<dim3(16, 16), 256, 0, stream>>>(W_out, wot, 1024, 1024);
    gemm_bt<<<dim3(64, 24), 256, 0, stream>>>(xb, wqt, b_qkv, 8192, 3072, 1024, 0,
                                              qbuf, kbuf, vbuf, nullptr);
    transpose_v<<<dim3(32, 64), 256, 0, stream>>>(vbuf, vtb);
    attn_kernel<<<dim3(16, 64), 256, 0, stream>>>(qbuf, kbuf, vtb, obuf);
    gemm_bt<<<dim3(64, 8), 256, 0, stream>>>(obuf, wot, b_out, 8192, 1024, 1024, 1,
                                             nullptr, nullptr, nullptr, out);
}

// Round 6
// 206.499 us; speedup vs baseline: 2.1512x; 1.0610x over previous
//
#include <hip/hip_runtime.h>
#include <hip/hip_bf16.h>

typedef unsigned short u16;
typedef unsigned u32;
typedef __attribute__((ext_vector_type(4))) unsigned short u16x4;
typedef __attribute__((ext_vector_type(8))) unsigned short u16x8;
typedef __attribute__((ext_vector_type(4))) unsigned u32x4;
typedef __attribute__((ext_vector_type(8))) __bf16 bf16x8;
typedef __attribute__((ext_vector_type(4))) float f32x4;

typedef __attribute__((address_space(1))) void as1v;
typedef __attribute__((address_space(3))) void as3v;

#define MFMA16(a, b, c) __builtin_amdgcn_mfma_f32_16x16x32_bf16(a, b, c, 0, 0, 0)

__device__ __forceinline__ u16 f2bf(float f) {
    unsigned u = __builtin_bit_cast(unsigned, f);
    u += 0x7fffu + ((u >> 16) & 1u);
    return (u16)(u >> 16);
}

__device__ __forceinline__ u32 pkbf(float lo, float hi) {
    u32 r;
    asm("v_cvt_pk_bf16_f32 %0, %1, %2" : "=v"(r) : "v"(lo), "v"(hi));
    return r;
}

__device__ __forceinline__ void gload16(const void* g, void* l) {
    __builtin_amdgcn_global_load_lds((as1v*)g, (as3v*)l, 16, 0, 0);
}

// ---------------------------------------------------------------------------
__global__ void convert_f32_bf16(const float* __restrict__ in, u16* __restrict__ out, int n4) {
    int i = blockIdx.x * blockDim.x + threadIdx.x;
    if (i < n4) {
        float4 v = *(const float4*)&in[(size_t)i * 4];
        u16x4 o;
        o.x = f2bf(v.x); o.y = f2bf(v.y); o.z = f2bf(v.z); o.w = f2bf(v.w);
        *(u16x4*)&out[(size_t)i * 4] = o;
    }
}

// ---------------------------------------------------------------------------
__global__ void transpose_convert(const float* __restrict__ in, u16* __restrict__ out, int R, int C) {
    __shared__ float tl[64][65];
    const int rb = blockIdx.x, cb = blockIdx.y;
    const int tid = threadIdx.x;
    for (int it = 0; it < 4; ++it) {
        int lin = (tid + it * 256) * 4;
        int r = lin >> 6, c = lin & 63;
        float4 v = *(const float4*)&in[(size_t)(rb * 64 + r) * C + cb * 64 + c];
        tl[r][c + 0] = v.x; tl[r][c + 1] = v.y; tl[r][c + 2] = v.z; tl[r][c + 3] = v.w;
    }
    __syncthreads();
    for (int it = 0; it < 4; ++it) {
        int lin = (tid + it * 256) * 4;
        int oc = lin >> 6, orr = lin & 63;
        u16x4 o;
        o.x = f2bf(tl[orr + 0][oc]);
        o.y = f2bf(tl[orr + 1][oc]);
        o.z = f2bf(tl[orr + 2][oc]);
        o.w = f2bf(tl[orr + 3][oc]);
        *(u16x4*)&out[(size_t)(cb * 64 + oc) * R + rb * 64 + orr] = o;
    }
}

// ---------------------------------------------------------------------------
__global__ void transpose_v(const u16* __restrict__ vbuf, u16* __restrict__ vtb) {
    __shared__ u16 tl[64][65];
    const int nb = blockIdx.x, bh = blockIdx.y;
    const int tid = threadIdx.x;
    for (int it = 0; it < 2; ++it) {
        int lin = (tid + it * 256) * 8;
        int nl = lin >> 6, dh = lin & 63;
        u16x8 v = *(const u16x8*)&vbuf[((size_t)bh * 2048 + nb * 64 + nl) * 64 + dh];
#pragma unroll
        for (int j = 0; j < 8; ++j) tl[dh + j][nl] = v[j];
    }
    __syncthreads();
    for (int it = 0; it < 2; ++it) {
        int lin = (tid + it * 256) * 8;
        int dh = lin >> 6, nl = lin & 63;
        u16x8 o;
#pragma unroll
        for (int j = 0; j < 8; ++j) o[j] = tl[dh][nl + j];
        *(u16x8*)&vtb[((size_t)bh * 64 + dh) * 2048 + nb * 64 + nl] = o;
    }
}

// ---------------------------------------------------------------------------
// QKV projection GEMM, deep-pipelined. M=8192, N=3072, K=1024 baked.
// 256x256 tile, BK=32, 8 waves (2M x 4N), 512 threads.
// LDS: 4-deep circular buffer x (A 16KB + B 16KB) = 128 KB.
//   Tile layout: 2 matrix rows packed per 128B LDS row; slot (16B unit) within
//   LDS row = ((r&1)*4 + k16) ^ ((r>>1)&7)  (self-inverse XOR swizzle,
//   applied on pre-swizzled global source + swizzled ds_read).
// Pipeline: computing tile t stages tile t+3 (buffer (t+3)&3 = (t-1)&3, whose
// reads completed before the previous barrier -> race-free). vmcnt(8) once per
// tile (all-but-8-newest landed => tile t+1 resident). Tail drains 8->4->0.
// Epilogue scatters bf16 into q/k/v buffers [b,h][n][64]; Q pre-scaled.
__global__ __launch_bounds__(512, 2) void gemm256_qkv(
    const u16* __restrict__ A, const u16* __restrict__ Bt, const float* __restrict__ bias,
    u16* __restrict__ qb, u16* __restrict__ kb, u16* __restrict__ vb) {
    constexpr int K = 1024;
    constexpr int NT = 32;          // K / 32
    __shared__ u16 ldsu[65536];     // 128 KB

    // XCD-aware swizzle over 384 blocks (384 % 8 == 0)
    const int bid = blockIdx.x;
    const int swz = (bid & 7) * 48 + (bid >> 3);
    const int bm = swz / 12, bn = swz % 12;

    const int tid = threadIdx.x, wid = tid >> 6, lane = tid & 63;
    const int wr = wid >> 2, wc = wid & 3;          // wave grid 2(M) x 4(N)
    const int l15 = lane & 15, lhi = lane >> 4;

    // --- staging source mapping (per lane) ---
    // dest (linear): buf + sg*1024B + lane*16B; ldsrow = sg*8 + (lane>>3),
    // destslot = lane&7; source slot = destslot ^ (ldsrow&7).
    const int sslot = (lane & 7) ^ (lane >> 3);
    const int kcol = (sslot & 3) * 8;                // k element offset
    // local matrix row within the per-load 16-row window:
    const int mloc = (lane >> 3) * 2 + (sslot >> 2); // 0..15

    const u16* Arow[2];
    const u16* Brow[2];
#pragma unroll
    for (int li = 0; li < 2; ++li) {
        int sg = wid * 2 + li;                       // segment 0..15
        int m = sg * 16 + mloc;                      // 0..255
        Arow[li] = A + (size_t)(bm * 256 + m) * K + kcol;
        Brow[li] = Bt + (size_t)(bn * 256 + m) * K + kcol;
    }

    auto stageA = [&](int buf, int t) {
#pragma unroll
        for (int li = 0; li < 2; ++li) {
            int sg = wid * 2 + li;
            gload16(Arow[li] + t * 32, (char*)ldsu + buf * 32768 + sg * 1024);
        }
    };
    auto stageB = [&](int buf, int t) {
#pragma unroll
        for (int li = 0; li < 2; ++li) {
            int sg = wid * 2 + li;
            gload16(Brow[li] + t * 32, (char*)ldsu + buf * 32768 + 16384 + sg * 1024);
        }
    };

    // --- fragment read offset (elements) ---
    // row R = base + f*16 + l15: ldsrow = R>>1, slot = ((R&1)*4+lhi)^((R>>1)&7)
    const int rslot = ((l15 & 1) * 4 + lhi) ^ ((l15 >> 1) & 7);
    const int fragoff = (l15 >> 1) * 64 + rslot * 8;

    f32x4 acc[8][4];
#pragma unroll
    for (int i = 0; i < 8; ++i)
#pragma unroll
        for (int j = 0; j < 4; ++j) acc[i][j] = (f32x4){0.f, 0.f, 0.f, 0.f};

    auto doTile = [&](int cur, int tstage, bool dostage) {
        const u16* Ab = ldsu + cur * 16384 + wr * 4096 + fragoff;
        const u16* Bb = ldsu + cur * 16384 + 8192 + wc * 2048 + fragoff;
        bf16x8 af[8], b0, b1;
        // ---- phase 1: nf 0,1 ----
#pragma unroll
        for (int mf = 0; mf < 8; ++mf) af[mf] = *(const bf16x8*)(Ab + mf * 512);
        b0 = *(const bf16x8*)(Bb);
        b1 = *(const bf16x8*)(Bb + 512);
        if (dostage) stageA(tstage & 3, tstage);
        __builtin_amdgcn_s_setprio(1);
#pragma unroll
        for (int mf = 0; mf < 8; ++mf) {
            acc[mf][0] = MFMA16(af[mf], b0, acc[mf][0]);
            acc[mf][1] = MFMA16(af[mf], b1, acc[mf][1]);
        }
        __builtin_amdgcn_s_setprio(0);
        // ---- phase 2: nf 2,3 ----
        b0 = *(const bf16x8*)(Bb + 1024);
        b1 = *(const bf16x8*)(Bb + 1536);
        if (dostage) stageB(tstage & 3, tstage);
        __builtin_amdgcn_s_setprio(1);
#pragma unroll
        for (int mf = 0; mf < 8; ++mf) {
            acc[mf][2] = MFMA16(af[mf], b0, acc[mf][2]);
            acc[mf][3] = MFMA16(af[mf], b1, acc[mf][3]);
        }
        __builtin_amdgcn_s_setprio(0);
    };

    // prologue: stage tiles 0,1,2 (12 loads); wait until tile 0 landed
    stageA(0, 0); stageB(0, 0);
    stageA(1, 1); stageB(1, 1);
    stageA(2, 2); stageB(2, 2);
    asm volatile("s_waitcnt vmcnt(8)" ::: "memory");
    __builtin_amdgcn_s_barrier();
    __builtin_amdgcn_sched_barrier(0);

    for (int t = 0; t < NT - 3; ++t) {
        doTile(t & 3, t + 3, true);
        asm volatile("s_waitcnt vmcnt(8)" ::: "memory");
        __builtin_amdgcn_s_barrier();
        __builtin_amdgcn_sched_barrier(0);
    }
    doTile((NT - 3) & 3, 0, false);
    asm volatile("s_waitcnt vmcnt(4)" ::: "memory");
    __builtin_amdgcn_s_barrier();
    __builtin_amdgcn_sched_barrier(0);
    doTile((NT - 2) & 3, 0, false);
    asm volatile("s_waitcnt vmcnt(0)" ::: "memory");
    __builtin_amdgcn_s_barrier();
    __builtin_amdgcn_sched_barrier(0);
    doTile((NT - 1) & 3, 0, false);

    // epilogue: scatter into q/k/v [b(4),h(16)][n(2048)][dh(64)]
    const int bnbase = bn * 256 + wc * 64;
#pragma unroll
    for (int nf = 0; nf < 4; ++nf) {
        int cg = bnbase + nf * 16 + l15;
        float bv = bias[cg];
        int which = cg >> 10, rem = cg & 1023;
        u16* dst = (which == 0) ? qb : (which == 1) ? kb : vb;
        float qs = (which == 0) ? 0.18033688011112042f : 1.0f;  // 0.125*log2e
        size_t colterm = (size_t)(rem >> 6) * 131072 + (size_t)(rem & 63);
#pragma unroll
        for (int mf = 0; mf < 8; ++mf) {
            int rgb = bm * 256 + wr * 128 + mf * 16 + lhi * 4;
            size_t rowterm = (size_t)(rgb >> 11) * 2097152 + (size_t)(rgb & 2047) * 64;
#pragma unroll
            for (int v = 0; v < 4; ++v) {
                float val = (acc[mf][nf][v] + bv) * qs;
                dst[rowterm + (size_t)v * 64 + colterm] = f2bf(val);
            }
        }
    }
}

// ---------------------------------------------------------------------------
// C = A[M][K] @ Bt[N][K]^T + bias.  128x128 tile, BK=32, 4 waves (2x2), each 64x64.
// (now used only for the output projection, mode 1)
__global__ __launch_bounds__(256) void gemm_bt(
    const u16* __restrict__ A, const u16* __restrict__ Bt, const float* __restrict__ bias,
    int M, int N, int K, int mode,
    u16* __restrict__ qb, u16* __restrict__ kb, u16* __restrict__ vb, float* __restrict__ outf) {
    __shared__ u16 Al[128 * 32];
    __shared__ u16 Bl[128 * 32];
    const int bm = blockIdx.x, bn = blockIdx.y;
    const int tid = threadIdx.x, wid = tid >> 6, lane = tid & 63;
    const int wr = wid >> 1, wc = wid & 1;
    const int l15 = lane & 15, lhi = lane >> 4;

    f32x4 acc[4][4];
#pragma unroll
    for (int i = 0; i < 4; ++i)
#pragma unroll
        for (int j = 0; j < 4; ++j) acc[i][j] = (f32x4){0.f, 0.f, 0.f, 0.f};

    for (int k0 = 0; k0 < K; k0 += 32) {
        __syncthreads();
#pragma unroll
        for (int s = 0; s < 2; ++s) {
            int lin0 = (wid * 2 + s) * 1024;
            int off = lin0 + lane * 16;
            int row = off >> 6, colb = off & 63;
            const u16* ga = A + (size_t)(bm * 128 + row) * K + k0 + (colb >> 1);
            gload16(ga, (char*)Al + lin0);
            const u16* gb = Bt + (size_t)(bn * 128 + row) * K + k0 + (colb >> 1);
            gload16(gb, (char*)Bl + lin0);
        }
        __syncthreads();
        bf16x8 af[4], bfr[4];
#pragma unroll
        for (int mt = 0; mt < 4; ++mt)
            af[mt] = *(const bf16x8*)&Al[(wr * 64 + mt * 16 + l15) * 32 + lhi * 8];
#pragma unroll
        for (int nt = 0; nt < 4; ++nt)
            bfr[nt] = *(const bf16x8*)&Bl[(wc * 64 + nt * 16 + l15) * 32 + lhi * 8];
#pragma unroll
        for (int mt = 0; mt < 4; ++mt)
#pragma unroll
            for (int nt = 0; nt < 4; ++nt)
                acc[mt][nt] = MFMA16(af[mt], bfr[nt], acc[mt][nt]);
    }

#pragma unroll
    for (int mt = 0; mt < 4; ++mt)
#pragma unroll
        for (int nt = 0; nt < 4; ++nt)
#pragma unroll
            for (int v = 0; v < 4; ++v) {
                int rg = bm * 128 + wr * 64 + mt * 16 + lhi * 4 + v;
                int cg = bn * 128 + wc * 64 + nt * 16 + l15;
                float val = acc[mt][nt][v] + bias[cg];
                if (mode == 0) {
                    int which = cg >> 10, rem = cg & 1023;
                    int hh = rem >> 6, dh = rem & 63;
                    int bb = rg >> 11, n = rg & 2047;
                    size_t idx = (((size_t)bb * 16 + hh) * 2048 + n) * 64 + dh;
                    if (which == 0) qb[idx] = f2bf(val * 0.18033688011112042f);
                    else if (which == 1) kb[idx] = f2bf(val);
                    else vb[idx] = f2bf(val);
                } else {
                    outf[(size_t)rg * N + cg] = val;
                }
            }
}

// ---------------------------------------------------------------------------
// Flash attention fwd, causal — 16x16x32 swapped-operand structure (verified r5).
__global__ __launch_bounds__(256, 2) void attn_kernel(
    const u16* __restrict__ qbuf, const u16* __restrict__ kbuf,
    const u16* __restrict__ vtb, u16* __restrict__ obuf) {
    __shared__ u16 Kl[2][64 * 64];
    __shared__ u16 Vl[2][64 * 64];
    const int p = blockIdx.x, bh = blockIdx.y;
    const int b = bh >> 4, h = bh & 15;
    const int tid = threadIdx.x, wid = tid >> 6, lane = tid & 63;
    const int l15 = lane & 15, lhi = lane >> 4;
    const int qA0 = p * 64 + wid * 16;
    const int qB0 = (31 - p) * 64 + wid * 16;
    const int ntA = p + 1;
    const int ntmax = 32 - p;   // == ntB for all waves

    bf16x8 qfA[2], qfB[2];
    {
        const u16* qa = qbuf + ((size_t)bh * 2048 + qA0 + l15) * 64 + lhi * 8;
        const u16* qbp = qbuf + ((size_t)bh * 2048 + qB0 + l15) * 64 + lhi * 8;
        qfA[0] = *(const bf16x8*)(qa);
        qfA[1] = *(const bf16x8*)(qa + 32);
        qfB[0] = *(const bf16x8*)(qbp);
        qfB[1] = *(const bf16x8*)(qbp + 32);
    }

    float mA = -1e30f, lA = 0.f, mB = -1e30f, lB = 0.f;
    f32x4 oA[4], oB[4];
#pragma unroll
    for (int d = 0; d < 4; ++d) {
        oA[d] = (f32x4){0.f, 0.f, 0.f, 0.f};
        oB[d] = (f32x4){0.f, 0.f, 0.f, 0.f};
    }

    const int srow = lane >> 3;
    const int scolb = ((lane & 7) * 16) ^ (srow << 4);

    auto stage = [&](int buf, int t) {
        const int kbase = t * 64;
#pragma unroll
        for (int s = 0; s < 2; ++s) {
            int sg = wid * 2 + s;
            int row = sg * 8 + srow;
            const u16* gk = kbuf + ((size_t)bh * 2048 + kbase + row) * 64 + (scolb >> 1);
            gload16(gk, (char*)Kl[buf] + sg * 1024);
            const u16* gv = vtb + ((size_t)bh * 64 + row) * 2048 + kbase + (scolb >> 1);
            gload16(gv, (char*)Vl[buf] + sg * 1024);
        }
    };

    auto computeTile = [&](int bufc, int t, int q0, const bf16x8* qf,
                           float& m, float& l, f32x4* oa) {
        const char* Kb = (const char*)Kl[bufc];
        const char* Vb = (const char*)Vl[bufc];
        f32x4 s[4];
        __builtin_amdgcn_s_setprio(1);
#pragma unroll
        for (int kb4 = 0; kb4 < 4; ++kb4) {
            const int r = kb4 * 16 + l15;
            const int sw = (r & 7) << 4;
            const int rowb = r * 128;
            f32x4 a = (f32x4){0.f, 0.f, 0.f, 0.f};
            a = MFMA16(*(const bf16x8*)(Kb + rowb + ((lhi * 16) ^ sw)), qf[0], a);
            a = MFMA16(*(const bf16x8*)(Kb + rowb + ((64 + lhi * 16) ^ sw)), qf[1], a);
            s[kb4] = a;
        }
        __builtin_amdgcn_s_setprio(0);
        const int qg = q0 + l15;
        if (64 * t + 63 > q0) {
#pragma unroll
            for (int kb4 = 0; kb4 < 4; ++kb4)
#pragma unroll
                for (int v = 0; v < 4; ++v) {
                    int kg = 64 * t + kb4 * 16 + lhi * 4 + v;
                    if (kg > qg) s[kb4][v] = -1e30f;
                }
        }
        float pm = fmaxf(fmaxf(fmaxf(s[0][0], s[0][1]), fmaxf(s[0][2], s[0][3])),
                         fmaxf(fmaxf(s[1][0], s[1][1]), fmaxf(s[1][2], s[1][3])));
        pm = fmaxf(pm, fmaxf(fmaxf(fmaxf(s[2][0], s[2][1]), fmaxf(s[2][2], s[2][3])),
                             fmaxf(fmaxf(s[3][0], s[3][1]), fmaxf(s[3][2], s[3][3]))));
        pm = fmaxf(pm, __shfl_xor(pm, 16, 64));
        pm = fmaxf(pm, __shfl_xor(pm, 32, 64));
        float nm = fmaxf(m, pm);
        float f = exp2f(m - nm);
        m = nm;
        float rs = 0.f;
#pragma unroll
        for (int kb4 = 0; kb4 < 4; ++kb4)
#pragma unroll
            for (int v = 0; v < 4; ++v) {
                float e = exp2f(s[kb4][v] - nm);
                s[kb4][v] = e;
                rs += e;
            }
        rs += __shfl_xor(rs, 16, 64);
        rs += __shfl_xor(rs, 32, 64);
        l = l * f + rs;
#pragma unroll
        for (int d = 0; d < 4; ++d)
#pragma unroll
            for (int v = 0; v < 4; ++v) oa[d][v] *= f;
        u32 pw0[4], pw1[4];
        pw0[0] = pkbf(s[0][0], s[0][1]); pw0[1] = pkbf(s[0][2], s[0][3]);
        pw0[2] = pkbf(s[1][0], s[1][1]); pw0[3] = pkbf(s[1][2], s[1][3]);
        pw1[0] = pkbf(s[2][0], s[2][1]); pw1[1] = pkbf(s[2][2], s[2][3]);
        pw1[2] = pkbf(s[3][0], s[3][1]); pw1[3] = pkbf(s[3][2], s[3][3]);
        __builtin_amdgcn_s_setprio(1);
#pragma unroll
        for (int ks = 0; ks < 2; ++ks) {
            bf16x8 pb = __builtin_bit_cast(bf16x8,
                ks == 0 ? (u32x4){pw0[0], pw0[1], pw0[2], pw0[3]}
                        : (u32x4){pw1[0], pw1[1], pw1[2], pw1[3]});
#pragma unroll
            for (int dhb = 0; dhb < 4; ++dhb) {
                const int r = dhb * 16 + l15;
                const int sw = (r & 7) << 4;
                u16x4 v0 = *(const u16x4*)(Vb + r * 128 + ((ks * 64 + 8 * lhi) ^ sw));
                u16x4 v1 = *(const u16x4*)(Vb + r * 128 + ((ks * 64 + 32 + 8 * lhi) ^ sw));
                u16x8 vv = {v0[0], v0[1], v0[2], v0[3], v1[0], v1[1], v1[2], v1[3]};
                oa[dhb] = MFMA16(__builtin_bit_cast(bf16x8, vv), pb, oa[dhb]);
            }
        }
        __builtin_amdgcn_s_setprio(0);
    };

    stage(0, 0);
    int cur = 0;
    for (int t = 0; t < ntmax; ++t) {
        __syncthreads();
        if (t + 1 < ntmax) stage(cur ^ 1, t + 1);
        computeTile(cur, t, qB0, qfB, mB, lB, oB);
        if (t < ntA) computeTile(cur, t, qA0, qfA, mA, lA, oA);
        cur ^= 1;
    }

    auto epi = [&](int q0, float l, const f32x4* oa) {
        const float rl = 1.f / l;
        const int q = q0 + l15;
        const size_t rowoff = ((size_t)b * 2048 + q) * 1024 + h * 64;
#pragma unroll
        for (int dhb = 0; dhb < 4; ++dhb) {
            u16x4 w;
#pragma unroll
            for (int v = 0; v < 4; ++v) w[v] = f2bf(oa[dhb][v] * rl);
            *(u16x4*)&obuf[rowoff + dhb * 16 + lhi * 4] = w;
        }
    };
    epi(qA0, lA, oA);
    epi(qB0, lB, oB);
}

// ---------------------------------------------------------------------------
extern "C" void kernel_launch(void* const* d_in, const int* in_sizes, int n_in,
                              void* d_out, int out_size, void* d_ws, size_t ws_size,
                              hipStream_t stream) {
    const float* inp   = (const float*)d_in[0];   // [4,2048,1024]
    const float* W_qkv = (const float*)d_in[1];   // [1024,3072]
    const float* b_qkv = (const float*)d_in[2];   // [3072]
    const float* W_out = (const float*)d_in[3];   // [1024,1024]
    const float* b_out = (const float*)d_in[4];   // [1024]
    float* out = (float*)d_out;                   // [4,2048,1024] f32

    u16* xb   = (u16*)d_ws;          // 8192x1024
    u16* wqt  = xb + 8388608;        // 3072x1024
    u16* wot  = wqt + 3145728;       // 1024x1024
    u16* qbuf = wot + 1048576;       // [64][2048][64]
    u16* kbuf = qbuf + 8388608;
    u16* vbuf = kbuf + 8388608;
    u16* vtb  = vbuf + 8388608;      // [64][64][2048]
    u16* obuf = vtb + 8388608;       // 8192x1024

    convert_f32_bf16<<<8192, 256, 0, stream>>>(inp, xb, 2097152);
    transpose_convert<<<dim3(16, 48), 256, 0, stream>>>(W_qkv, wqt, 1024, 3072);
    transpose_convert<<<dim3(16, 16), 256, 0, stream>>>(W_out, wot, 1024, 1024);
    gemm256_qkv<<<384, 512, 0, stream>>>(xb, wqt, b_qkv, qbuf, kbuf, vbuf);
    transpose_v<<<dim3(32, 64), 256, 0, stream>>>(vbuf, vtb);
    attn_kernel<<<dim3(16, 64), 256, 0, stream>>>(qbuf, kbuf, vtb, obuf);
    gemm_bt<<<dim3(64, 8), 256, 0, stream>>>(obuf, wot, b_out, 8192, 1024, 1024, 1,
                                             nullptr, nullptr, nullptr, out);
}

// Round 7
// 203.133 us; speedup vs baseline: 2.1869x; 1.0166x over previous
//
#include <hip/hip_runtime.h>
#include <hip/hip_bf16.h>

typedef unsigned short u16;
typedef unsigned u32;
typedef __attribute__((ext_vector_type(4))) unsigned short u16x4;
typedef __attribute__((ext_vector_type(8))) unsigned short u16x8;
typedef __attribute__((ext_vector_type(4))) unsigned u32x4;
typedef __attribute__((ext_vector_type(8))) __bf16 bf16x8;
typedef __attribute__((ext_vector_type(4))) float f32x4;

typedef __attribute__((address_space(1))) void as1v;
typedef __attribute__((address_space(3))) void as3v;

#define MFMA16(a, b, c) __builtin_amdgcn_mfma_f32_16x16x32_bf16(a, b, c, 0, 0, 0)

__device__ __forceinline__ u16 f2bf(float f) {
    unsigned u = __builtin_bit_cast(unsigned, f);
    u += 0x7fffu + ((u >> 16) & 1u);
    return (u16)(u >> 16);
}

__device__ __forceinline__ u32 pkbf(float lo, float hi) {
    u32 r;
    asm("v_cvt_pk_bf16_f32 %0, %1, %2" : "=v"(r) : "v"(lo), "v"(hi));
    return r;
}

__device__ __forceinline__ void gload16(const void* g, void* l) {
    __builtin_amdgcn_global_load_lds((as1v*)g, (as3v*)l, 16, 0, 0);
}

// ---------------------------------------------------------------------------
__global__ void convert_f32_bf16(const float* __restrict__ in, u16* __restrict__ out, int n4) {
    int i = blockIdx.x * blockDim.x + threadIdx.x;
    if (i < n4) {
        float4 v = *(const float4*)&in[(size_t)i * 4];
        u16x4 o;
        o.x = f2bf(v.x); o.y = f2bf(v.y); o.z = f2bf(v.z); o.w = f2bf(v.w);
        *(u16x4*)&out[(size_t)i * 4] = o;
    }
}

// ---------------------------------------------------------------------------
__global__ void transpose_convert(const float* __restrict__ in, u16* __restrict__ out, int R, int C) {
    __shared__ float tl[64][65];
    const int rb = blockIdx.x, cb = blockIdx.y;
    const int tid = threadIdx.x;
    for (int it = 0; it < 4; ++it) {
        int lin = (tid + it * 256) * 4;
        int r = lin >> 6, c = lin & 63;
        float4 v = *(const float4*)&in[(size_t)(rb * 64 + r) * C + cb * 64 + c];
        tl[r][c + 0] = v.x; tl[r][c + 1] = v.y; tl[r][c + 2] = v.z; tl[r][c + 3] = v.w;
    }
    __syncthreads();
    for (int it = 0; it < 4; ++it) {
        int lin = (tid + it * 256) * 4;
        int oc = lin >> 6, orr = lin & 63;
        u16x4 o;
        o.x = f2bf(tl[orr + 0][oc]);
        o.y = f2bf(tl[orr + 1][oc]);
        o.z = f2bf(tl[orr + 2][oc]);
        o.w = f2bf(tl[orr + 3][oc]);
        *(u16x4*)&out[(size_t)(cb * 64 + oc) * R + rb * 64 + orr] = o;
    }
}

// ---------------------------------------------------------------------------
__global__ void transpose_v(const u16* __restrict__ vbuf, u16* __restrict__ vtb) {
    __shared__ u16 tl[64][65];
    const int nb = blockIdx.x, bh = blockIdx.y;
    const int tid = threadIdx.x;
    for (int it = 0; it < 2; ++it) {
        int lin = (tid + it * 256) * 8;
        int nl = lin >> 6, dh = lin & 63;
        u16x8 v = *(const u16x8*)&vbuf[((size_t)bh * 2048 + nb * 64 + nl) * 64 + dh];
#pragma unroll
        for (int j = 0; j < 8; ++j) tl[dh + j][nl] = v[j];
    }
    __syncthreads();
    for (int it = 0; it < 2; ++it) {
        int lin = (tid + it * 256) * 8;
        int dh = lin >> 6, nl = lin & 63;
        u16x8 o;
#pragma unroll
        for (int j = 0; j < 8; ++j) o[j] = tl[dh][nl + j];
        *(u16x8*)&vtb[((size_t)bh * 64 + dh) * 2048 + nb * 64 + nl] = o;
    }
}

// ---------------------------------------------------------------------------
// QKV projection GEMM, deep-pipelined (verified r6). M=8192,N=3072,K=1024.
__global__ __launch_bounds__(512, 2) void gemm256_qkv(
    const u16* __restrict__ A, const u16* __restrict__ Bt, const float* __restrict__ bias,
    u16* __restrict__ qb, u16* __restrict__ kb, u16* __restrict__ vb) {
    constexpr int K = 1024;
    constexpr int NT = 32;
    __shared__ u16 ldsu[65536];

    const int bid = blockIdx.x;
    const int swz = (bid & 7) * 48 + (bid >> 3);
    const int bm = swz / 12, bn = swz % 12;

    const int tid = threadIdx.x, wid = tid >> 6, lane = tid & 63;
    const int wr = wid >> 2, wc = wid & 3;
    const int l15 = lane & 15, lhi = lane >> 4;

    const int sslot = (lane & 7) ^ (lane >> 3);
    const int kcol = (sslot & 3) * 8;
    const int mloc = (lane >> 3) * 2 + (sslot >> 2);

    const u16* Arow[2];
    const u16* Brow[2];
#pragma unroll
    for (int li = 0; li < 2; ++li) {
        int sg = wid * 2 + li;
        int m = sg * 16 + mloc;
        Arow[li] = A + (size_t)(bm * 256 + m) * K + kcol;
        Brow[li] = Bt + (size_t)(bn * 256 + m) * K + kcol;
    }

    auto stageA = [&](int buf, int t) {
#pragma unroll
        for (int li = 0; li < 2; ++li) {
            int sg = wid * 2 + li;
            gload16(Arow[li] + t * 32, (char*)ldsu + buf * 32768 + sg * 1024);
        }
    };
    auto stageB = [&](int buf, int t) {
#pragma unroll
        for (int li = 0; li < 2; ++li) {
            int sg = wid * 2 + li;
            gload16(Brow[li] + t * 32, (char*)ldsu + buf * 32768 + 16384 + sg * 1024);
        }
    };

    const int rslot = ((l15 & 1) * 4 + lhi) ^ ((l15 >> 1) & 7);
    const int fragoff = (l15 >> 1) * 64 + rslot * 8;

    f32x4 acc[8][4];
#pragma unroll
    for (int i = 0; i < 8; ++i)
#pragma unroll
        for (int j = 0; j < 4; ++j) acc[i][j] = (f32x4){0.f, 0.f, 0.f, 0.f};

    auto doTile = [&](int cur, int tstage, bool dostage) {
        const u16* Ab = ldsu + cur * 16384 + wr * 4096 + fragoff;
        const u16* Bb = ldsu + cur * 16384 + 8192 + wc * 2048 + fragoff;
        bf16x8 af[8], b0, b1;
#pragma unroll
        for (int mf = 0; mf < 8; ++mf) af[mf] = *(const bf16x8*)(Ab + mf * 512);
        b0 = *(const bf16x8*)(Bb);
        b1 = *(const bf16x8*)(Bb + 512);
        if (dostage) stageA(tstage & 3, tstage);
        __builtin_amdgcn_s_setprio(1);
#pragma unroll
        for (int mf = 0; mf < 8; ++mf) {
            acc[mf][0] = MFMA16(af[mf], b0, acc[mf][0]);
            acc[mf][1] = MFMA16(af[mf], b1, acc[mf][1]);
        }
        __builtin_amdgcn_s_setprio(0);
        b0 = *(const bf16x8*)(Bb + 1024);
        b1 = *(const bf16x8*)(Bb + 1536);
        if (dostage) stageB(tstage & 3, tstage);
        __builtin_amdgcn_s_setprio(1);
#pragma unroll
        for (int mf = 0; mf < 8; ++mf) {
            acc[mf][2] = MFMA16(af[mf], b0, acc[mf][2]);
            acc[mf][3] = MFMA16(af[mf], b1, acc[mf][3]);
        }
        __builtin_amdgcn_s_setprio(0);
    };

    stageA(0, 0); stageB(0, 0);
    stageA(1, 1); stageB(1, 1);
    stageA(2, 2); stageB(2, 2);
    asm volatile("s_waitcnt vmcnt(8)" ::: "memory");
    __builtin_amdgcn_s_barrier();
    __builtin_amdgcn_sched_barrier(0);

    for (int t = 0; t < NT - 3; ++t) {
        doTile(t & 3, t + 3, true);
        asm volatile("s_waitcnt vmcnt(8)" ::: "memory");
        __builtin_amdgcn_s_barrier();
        __builtin_amdgcn_sched_barrier(0);
    }
    doTile((NT - 3) & 3, 0, false);
    asm volatile("s_waitcnt vmcnt(4)" ::: "memory");
    __builtin_amdgcn_s_barrier();
    __builtin_amdgcn_sched_barrier(0);
    doTile((NT - 2) & 3, 0, false);
    asm volatile("s_waitcnt vmcnt(0)" ::: "memory");
    __builtin_amdgcn_s_barrier();
    __builtin_amdgcn_sched_barrier(0);
    doTile((NT - 1) & 3, 0, false);

    const int bnbase = bn * 256 + wc * 64;
#pragma unroll
    for (int nf = 0; nf < 4; ++nf) {
        int cg = bnbase + nf * 16 + l15;
        float bv = bias[cg];
        int which = cg >> 10, rem = cg & 1023;
        u16* dst = (which == 0) ? qb : (which == 1) ? kb : vb;
        float qs = (which == 0) ? 0.18033688011112042f : 1.0f;
        size_t colterm = (size_t)(rem >> 6) * 131072 + (size_t)(rem & 63);
#pragma unroll
        for (int mf = 0; mf < 8; ++mf) {
            int rgb = bm * 256 + wr * 128 + mf * 16 + lhi * 4;
            size_t rowterm = (size_t)(rgb >> 11) * 2097152 + (size_t)(rgb & 2047) * 64;
#pragma unroll
            for (int v = 0; v < 4; ++v) {
                float val = (acc[mf][nf][v] + bv) * qs;
                dst[rowterm + (size_t)v * 64 + colterm] = f2bf(val);
            }
        }
    }
}

// ---------------------------------------------------------------------------
// Output projection GEMM (128x128, verified structure).
__global__ __launch_bounds__(256) void gemm_bt(
    const u16* __restrict__ A, const u16* __restrict__ Bt, const float* __restrict__ bias,
    int M, int N, int K, float* __restrict__ outf) {
    __shared__ u16 Al[128 * 32];
    __shared__ u16 Bl[128 * 32];
    const int bm = blockIdx.x, bn = blockIdx.y;
    const int tid = threadIdx.x, wid = tid >> 6, lane = tid & 63;
    const int wr = wid >> 1, wc = wid & 1;
    const int l15 = lane & 15, lhi = lane >> 4;

    f32x4 acc[4][4];
#pragma unroll
    for (int i = 0; i < 4; ++i)
#pragma unroll
        for (int j = 0; j < 4; ++j) acc[i][j] = (f32x4){0.f, 0.f, 0.f, 0.f};

    for (int k0 = 0; k0 < K; k0 += 32) {
        __syncthreads();
#pragma unroll
        for (int s = 0; s < 2; ++s) {
            int lin0 = (wid * 2 + s) * 1024;
            int off = lin0 + lane * 16;
            int row = off >> 6, colb = off & 63;
            const u16* ga = A + (size_t)(bm * 128 + row) * K + k0 + (colb >> 1);
            gload16(ga, (char*)Al + lin0);
            const u16* gb = Bt + (size_t)(bn * 128 + row) * K + k0 + (colb >> 1);
            gload16(gb, (char*)Bl + lin0);
        }
        __syncthreads();
        bf16x8 af[4], bfr[4];
#pragma unroll
        for (int mt = 0; mt < 4; ++mt)
            af[mt] = *(const bf16x8*)&Al[(wr * 64 + mt * 16 + l15) * 32 + lhi * 8];
#pragma unroll
        for (int nt = 0; nt < 4; ++nt)
            bfr[nt] = *(const bf16x8*)&Bl[(wc * 64 + nt * 16 + l15) * 32 + lhi * 8];
#pragma unroll
        for (int mt = 0; mt < 4; ++mt)
#pragma unroll
            for (int nt = 0; nt < 4; ++nt)
                acc[mt][nt] = MFMA16(af[mt], bfr[nt], acc[mt][nt]);
    }

#pragma unroll
    for (int mt = 0; mt < 4; ++mt)
#pragma unroll
        for (int nt = 0; nt < 4; ++nt)
#pragma unroll
            for (int v = 0; v < 4; ++v) {
                int rg = bm * 128 + wr * 64 + mt * 16 + lhi * 4 + v;
                int cg = bn * 128 + wc * 64 + nt * 16 + l15;
                outf[(size_t)rg * N + cg] = acc[mt][nt][v] + bias[cg];
            }
}

// ---------------------------------------------------------------------------
// Flash attention fwd, causal — 16x16x32 swapped-operand (math verified r5),
// restructured for LDS-read amortization:
//  - 128-q chunks, block = pair (c, 15-c), 8 pairs x 64 bh = 512 blocks.
//  - Wave: 32 q per chunk = 2 q-groups of 16; K-frag and V-frag LDS reads
//    shared by both groups (2 MFMAs per fragment read) -> LDS bytes/S-elem /2.
//  - XCD clustering: bh = (bid&7)*8 + (bid>>6) -> all 8 blocks of a bh on one
//    XCD's L2 (K/V re-fetch served from L2, not HBM).
//  - Static double-buffer unroll (LDS addrs loop-invariant), defer-max (THR=8).
__global__ __launch_bounds__(256, 2) void attn_kernel(
    const u16* __restrict__ qbuf, const u16* __restrict__ kbuf,
    const u16* __restrict__ vtb, u16* __restrict__ obuf) {
    __shared__ u16 Kl[2][64 * 64];
    __shared__ u16 Vl[2][64 * 64];
    const int bid = blockIdx.x;
    const int c = (bid >> 3) & 7;
    const int bh = ((bid & 7) << 3) + (bid >> 6);
    const int b = bh >> 4, h = bh & 15;
    const int tid = threadIdx.x, wid = tid >> 6, lane = tid & 63;
    const int l15 = lane & 15, lhi = lane >> 4;
    const int qA0 = c * 128 + wid * 32;          // chunk A (small), groups at +0,+16
    const int qB0 = (15 - c) * 128 + wid * 32;   // chunk B (large)
    const int ntA = 2 * c + (wid >> 1) + 1;
    const int ntB = 31 - 2 * c + (wid >> 1);
    const int ntmax = 32 - 2 * c;

    auto loadQ = [&](int qbase, bf16x8* dst) {
        const u16* qp = qbuf + ((size_t)bh * 2048 + qbase + l15) * 64 + lhi * 8;
        dst[0] = *(const bf16x8*)(qp);
        dst[1] = *(const bf16x8*)(qp + 32);
    };
    bf16x8 qfA0[2], qfA1[2], qfB0[2], qfB1[2];
    loadQ(qA0, qfA0); loadQ(qA0 + 16, qfA1);
    loadQ(qB0, qfB0); loadQ(qB0 + 16, qfB1);

    float mA0 = -1e30f, lA0 = 0.f, mA1 = -1e30f, lA1 = 0.f;
    float mB0 = -1e30f, lB0 = 0.f, mB1 = -1e30f, lB1 = 0.f;
    f32x4 oA0[4], oA1[4], oB0[4], oB1[4];
#pragma unroll
    for (int d = 0; d < 4; ++d) {
        oA0[d] = (f32x4){0.f, 0.f, 0.f, 0.f}; oA1[d] = (f32x4){0.f, 0.f, 0.f, 0.f};
        oB0[d] = (f32x4){0.f, 0.f, 0.f, 0.f}; oB1[d] = (f32x4){0.f, 0.f, 0.f, 0.f};
    }

    const int srow = lane >> 3;
    const int scolb = ((lane & 7) * 16) ^ (srow << 4);

    auto stage = [&](int buf, int t) {
        const int kbase = t * 64;
#pragma unroll
        for (int s = 0; s < 2; ++s) {
            int sg = wid * 2 + s;
            int row = sg * 8 + srow;
            const u16* gk = kbuf + ((size_t)bh * 2048 + kbase + row) * 64 + (scolb >> 1);
            gload16(gk, (char*)Kl[buf] + sg * 1024);
            const u16* gv = vtb + ((size_t)bh * 64 + row) * 2048 + kbase + (scolb >> 1);
            gload16(gv, (char*)Vl[buf] + sg * 1024);
        }
    };

    // masking + online softmax + P-pack for one 16-q group (defer-max THR=8)
    auto smax = [&](f32x4* s, int qg0, int t, float& m, float& l, f32x4* oa, u32* pw) {
        const int qg = qg0 + l15;
        if (64 * t + 63 > qg0) {
#pragma unroll
            for (int kb4 = 0; kb4 < 4; ++kb4)
#pragma unroll
                for (int v = 0; v < 4; ++v) {
                    int kg = 64 * t + kb4 * 16 + lhi * 4 + v;
                    if (kg > qg) s[kb4][v] = -1e30f;
                }
        }
        float pm = fmaxf(fmaxf(fmaxf(s[0][0], s[0][1]), fmaxf(s[0][2], s[0][3])),
                         fmaxf(fmaxf(s[1][0], s[1][1]), fmaxf(s[1][2], s[1][3])));
        pm = fmaxf(pm, fmaxf(fmaxf(fmaxf(s[2][0], s[2][1]), fmaxf(s[2][2], s[2][3])),
                             fmaxf(fmaxf(s[3][0], s[3][1]), fmaxf(s[3][2], s[3][3]))));
        pm = fmaxf(pm, __shfl_xor(pm, 16, 64));
        pm = fmaxf(pm, __shfl_xor(pm, 32, 64));
        if (!__all(pm <= m + 8.f)) {
            float nm = fmaxf(m, pm);
            float f = exp2f(m - nm);
            m = nm;
            l *= f;
#pragma unroll
            for (int d = 0; d < 4; ++d)
#pragma unroll
                for (int v = 0; v < 4; ++v) oa[d][v] *= f;
        }
        float rs = 0.f;
#pragma unroll
        for (int kb4 = 0; kb4 < 4; ++kb4)
#pragma unroll
            for (int v = 0; v < 4; ++v) {
                float e = exp2f(s[kb4][v] - m);
                s[kb4][v] = e;
                rs += e;
            }
        rs += __shfl_xor(rs, 16, 64);
        rs += __shfl_xor(rs, 32, 64);
        l += rs;
        pw[0] = pkbf(s[0][0], s[0][1]); pw[1] = pkbf(s[0][2], s[0][3]);
        pw[2] = pkbf(s[1][0], s[1][1]); pw[3] = pkbf(s[1][2], s[1][3]);
        pw[4] = pkbf(s[2][0], s[2][1]); pw[5] = pkbf(s[2][2], s[2][3]);
        pw[6] = pkbf(s[3][0], s[3][1]); pw[7] = pkbf(s[3][2], s[3][3]);
    };

    // one chunk (2 groups) against tile t; K/V frags read once, used twice
    auto computeChunk = [&](const char* Kb, const char* Vb, int t, int q0,
                            const bf16x8* qf0, const bf16x8* qf1,
                            float& m0, float& l0, f32x4* oa0,
                            float& m1, float& l1, f32x4* oa1) {
        f32x4 s0[4], s1[4];
        __builtin_amdgcn_s_setprio(1);
#pragma unroll
        for (int kb4 = 0; kb4 < 4; ++kb4) {
            const int r = kb4 * 16 + l15;
            const int sw = (r & 7) << 4;
            const int rowb = r * 128;
            bf16x8 kf0 = *(const bf16x8*)(Kb + rowb + ((lhi * 16) ^ sw));
            bf16x8 kf1 = *(const bf16x8*)(Kb + rowb + ((64 + lhi * 16) ^ sw));
            f32x4 a0 = (f32x4){0.f, 0.f, 0.f, 0.f};
            a0 = MFMA16(kf0, qf0[0], a0);
            a0 = MFMA16(kf1, qf0[1], a0);
            s0[kb4] = a0;
            f32x4 a1 = (f32x4){0.f, 0.f, 0.f, 0.f};
            a1 = MFMA16(kf0, qf1[0], a1);
            a1 = MFMA16(kf1, qf1[1], a1);
            s1[kb4] = a1;
        }
        __builtin_amdgcn_s_setprio(0);
        u32 pw0[8], pw1[8];
        smax(s0, q0, t, m0, l0, oa0, pw0);
        smax(s1, q0 + 16, t, m1, l1, oa1, pw1);
        __builtin_amdgcn_s_setprio(1);
#pragma unroll
        for (int ks = 0; ks < 2; ++ks) {
            bf16x8 pb0 = __builtin_bit_cast(bf16x8,
                (u32x4){pw0[ks * 4 + 0], pw0[ks * 4 + 1], pw0[ks * 4 + 2], pw0[ks * 4 + 3]});
            bf16x8 pb1 = __builtin_bit_cast(bf16x8,
                (u32x4){pw1[ks * 4 + 0], pw1[ks * 4 + 1], pw1[ks * 4 + 2], pw1[ks * 4 + 3]});
#pragma unroll
            for (int dhb = 0; dhb < 4; ++dhb) {
                const int r = dhb * 16 + l15;
                const int sw = (r & 7) << 4;
                u16x4 v0 = *(const u16x4*)(Vb + r * 128 + ((ks * 64 + 8 * lhi) ^ sw));
                u16x4 v1 = *(const u16x4*)(Vb + r * 128 + ((ks * 64 + 32 + 8 * lhi) ^ sw));
                u16x8 vv = {v0[0], v0[1], v0[2], v0[3], v1[0], v1[1], v1[2], v1[3]};
                bf16x8 vf = __builtin_bit_cast(bf16x8, vv);
                oa0[dhb] = MFMA16(vf, pb0, oa0[dhb]);
                oa1[dhb] = MFMA16(vf, pb1, oa1[dhb]);
            }
        }
        __builtin_amdgcn_s_setprio(0);
    };

    auto step = [&](const char* Kb, const char* Vb, int t) {
        if (t < ntB) computeChunk(Kb, Vb, t, qB0, qfB0, qfB1, mB0, lB0, oB0, mB1, lB1, oB1);
        if (t < ntA) computeChunk(Kb, Vb, t, qA0, qfA0, qfA1, mA0, lA0, oA0, mA1, lA1, oA1);
    };

    stage(0, 0);
    int t = 0;
    for (;;) {
        __syncthreads();
        if (t + 1 < ntmax) stage(1, t + 1);
        step((const char*)Kl[0], (const char*)Vl[0], t);
        if (++t == ntmax) break;
        __syncthreads();
        if (t + 1 < ntmax) stage(0, t + 1);
        step((const char*)Kl[1], (const char*)Vl[1], t);
        if (++t == ntmax) break;
    }

    auto epi = [&](int q0, float l, const f32x4* oa) {
        const float rl = 1.f / l;
        const int q = q0 + l15;
        const size_t rowoff = ((size_t)b * 2048 + q) * 1024 + h * 64;
#pragma unroll
        for (int dhb = 0; dhb < 4; ++dhb) {
            u16x4 w;
#pragma unroll
            for (int v = 0; v < 4; ++v) w[v] = f2bf(oa[dhb][v] * rl);
            *(u16x4*)&obuf[rowoff + dhb * 16 + lhi * 4] = w;
        }
    };
    epi(qA0, lA0, oA0);
    epi(qA0 + 16, lA1, oA1);
    epi(qB0, lB0, oB0);
    epi(qB0 + 16, lB1, oB1);
}

// ---------------------------------------------------------------------------
extern "C" void kernel_launch(void* const* d_in, const int* in_sizes, int n_in,
                              void* d_out, int out_size, void* d_ws, size_t ws_size,
                              hipStream_t stream) {
    const float* inp   = (const float*)d_in[0];   // [4,2048,1024]
    const float* W_qkv = (const float*)d_in[1];   // [1024,3072]
    const float* b_qkv = (const float*)d_in[2];   // [3072]
    const float* W_out = (const float*)d_in[3];   // [1024,1024]
    const float* b_out = (const float*)d_in[4];   // [1024]
    float* out = (float*)d_out;                   // [4,2048,1024] f32

    u16* xb   = (u16*)d_ws;          // 8192x1024
    u16* wqt  = xb + 8388608;        // 3072x1024
    u16* wot  = wqt + 3145728;       // 1024x1024
    u16* qbuf = wot + 1048576;       // [64][2048][64]
    u16* kbuf = qbuf + 8388608;
    u16* vbuf = kbuf + 8388608;
    u16* vtb  = vbuf + 8388608;      // [64][64][2048]
    u16* obuf = vtb + 8388608;       // 8192x1024

    convert_f32_bf16<<<8192, 256, 0, stream>>>(inp, xb, 2097152);
    transpose_convert<<<dim3(16, 48), 256, 0, stream>>>(W_qkv, wqt, 1024, 3072);
    transpose_convert<<<dim3(16, 16), 256, 0, stream>>>(W_out, wot, 1024, 1024);
    gemm256_qkv<<<384, 512, 0, stream>>>(xb, wqt, b_qkv, qbuf, kbuf, vbuf);
    transpose_v<<<dim3(32, 64), 256, 0, stream>>>(vbuf, vtb);
    attn_kernel<<<512, 256, 0, stream>>>(qbuf, kbuf, vtb, obuf);
    gemm_bt<<<dim3(64, 8), 256, 0, stream>>>(obuf, wot, b_out, 8192, 1024, 1024, out);
}

// Round 8
// 191.952 us; speedup vs baseline: 2.3143x; 1.0582x over previous
//
#include <hip/hip_runtime.h>
#include <hip/hip_bf16.h>

typedef unsigned short u16;
typedef unsigned u32;
typedef __attribute__((ext_vector_type(4))) unsigned short u16x4;
typedef __attribute__((ext_vector_type(8))) unsigned short u16x8;
typedef __attribute__((ext_vector_type(4))) unsigned u32x4;
typedef __attribute__((ext_vector_type(8))) __bf16 bf16x8;
typedef __attribute__((ext_vector_type(4))) float f32x4;

typedef __attribute__((address_space(1))) void as1v;
typedef __attribute__((address_space(3))) void as3v;

#define MFMA16(a, b, c) __builtin_amdgcn_mfma_f32_16x16x32_bf16(a, b, c, 0, 0, 0)

__device__ __forceinline__ u16 f2bf(float f) {
    unsigned u = __builtin_bit_cast(unsigned, f);
    u += 0x7fffu + ((u >> 16) & 1u);
    return (u16)(u >> 16);
}

__device__ __forceinline__ u32 pkbf(float lo, float hi) {
    u32 r;
    asm("v_cvt_pk_bf16_f32 %0, %1, %2" : "=v"(r) : "v"(lo), "v"(hi));
    return r;
}

__device__ __forceinline__ void gload16(const void* g, void* l) {
    __builtin_amdgcn_global_load_lds((as1v*)g, (as3v*)l, 16, 0, 0);
}

// ---------------------------------------------------------------------------
__global__ void convert_f32_bf16(const float* __restrict__ in, u16* __restrict__ out, int n4) {
    int i = blockIdx.x * blockDim.x + threadIdx.x;
    if (i < n4) {
        float4 v = *(const float4*)&in[(size_t)i * 4];
        u16x4 o;
        o.x = f2bf(v.x); o.y = f2bf(v.y); o.z = f2bf(v.z); o.w = f2bf(v.w);
        *(u16x4*)&out[(size_t)i * 4] = o;
    }
}

// ---------------------------------------------------------------------------
__global__ void transpose_convert(const float* __restrict__ in, u16* __restrict__ out, int R, int C) {
    __shared__ float tl[64][65];
    const int rb = blockIdx.x, cb = blockIdx.y;
    const int tid = threadIdx.x;
    for (int it = 0; it < 4; ++it) {
        int lin = (tid + it * 256) * 4;
        int r = lin >> 6, c = lin & 63;
        float4 v = *(const float4*)&in[(size_t)(rb * 64 + r) * C + cb * 64 + c];
        tl[r][c + 0] = v.x; tl[r][c + 1] = v.y; tl[r][c + 2] = v.z; tl[r][c + 3] = v.w;
    }
    __syncthreads();
    for (int it = 0; it < 4; ++it) {
        int lin = (tid + it * 256) * 4;
        int oc = lin >> 6, orr = lin & 63;
        u16x4 o;
        o.x = f2bf(tl[orr + 0][oc]);
        o.y = f2bf(tl[orr + 1][oc]);
        o.z = f2bf(tl[orr + 2][oc]);
        o.w = f2bf(tl[orr + 3][oc]);
        *(u16x4*)&out[(size_t)(cb * 64 + oc) * R + rb * 64 + orr] = o;
    }
}

// ---------------------------------------------------------------------------
__global__ void transpose_v(const u16* __restrict__ vbuf, u16* __restrict__ vtb) {
    __shared__ u16 tl[64][65];
    const int nb = blockIdx.x, bh = blockIdx.y;
    const int tid = threadIdx.x;
    for (int it = 0; it < 2; ++it) {
        int lin = (tid + it * 256) * 8;
        int nl = lin >> 6, dh = lin & 63;
        u16x8 v = *(const u16x8*)&vbuf[((size_t)bh * 2048 + nb * 64 + nl) * 64 + dh];
#pragma unroll
        for (int j = 0; j < 8; ++j) tl[dh + j][nl] = v[j];
    }
    __syncthreads();
    for (int it = 0; it < 2; ++it) {
        int lin = (tid + it * 256) * 8;
        int dh = lin >> 6, nl = lin & 63;
        u16x8 o;
#pragma unroll
        for (int j = 0; j < 8; ++j) o[j] = tl[dh][nl + j];
        *(u16x8*)&vtb[((size_t)bh * 64 + dh) * 2048 + nb * 64 + nl] = o;
    }
}

// ---------------------------------------------------------------------------
// QKV projection GEMM, deep-pipelined (verified r6). M=8192,N=3072,K=1024.
__global__ __launch_bounds__(512, 2) void gemm256_qkv(
    const u16* __restrict__ A, const u16* __restrict__ Bt, const float* __restrict__ bias,
    u16* __restrict__ qb, u16* __restrict__ kb, u16* __restrict__ vb) {
    constexpr int K = 1024;
    constexpr int NT = 32;
    __shared__ u16 ldsu[65536];

    const int bid = blockIdx.x;
    const int swz = (bid & 7) * 48 + (bid >> 3);
    const int bm = swz / 12, bn = swz % 12;

    const int tid = threadIdx.x, wid = tid >> 6, lane = tid & 63;
    const int wr = wid >> 2, wc = wid & 3;
    const int l15 = lane & 15, lhi = lane >> 4;

    const int sslot = (lane & 7) ^ (lane >> 3);
    const int kcol = (sslot & 3) * 8;
    const int mloc = (lane >> 3) * 2 + (sslot >> 2);

    const u16* Arow[2];
    const u16* Brow[2];
#pragma unroll
    for (int li = 0; li < 2; ++li) {
        int sg = wid * 2 + li;
        int m = sg * 16 + mloc;
        Arow[li] = A + (size_t)(bm * 256 + m) * K + kcol;
        Brow[li] = Bt + (size_t)(bn * 256 + m) * K + kcol;
    }

    auto stageA = [&](int buf, int t) {
#pragma unroll
        for (int li = 0; li < 2; ++li) {
            int sg = wid * 2 + li;
            gload16(Arow[li] + t * 32, (char*)ldsu + buf * 32768 + sg * 1024);
        }
    };
    auto stageB = [&](int buf, int t) {
#pragma unroll
        for (int li = 0; li < 2; ++li) {
            int sg = wid * 2 + li;
            gload16(Brow[li] + t * 32, (char*)ldsu + buf * 32768 + 16384 + sg * 1024);
        }
    };

    const int rslot = ((l15 & 1) * 4 + lhi) ^ ((l15 >> 1) & 7);
    const int fragoff = (l15 >> 1) * 64 + rslot * 8;

    f32x4 acc[8][4];
#pragma unroll
    for (int i = 0; i < 8; ++i)
#pragma unroll
        for (int j = 0; j < 4; ++j) acc[i][j] = (f32x4){0.f, 0.f, 0.f, 0.f};

    auto doTile = [&](int cur, int tstage, bool dostage) {
        const u16* Ab = ldsu + cur * 16384 + wr * 4096 + fragoff;
        const u16* Bb = ldsu + cur * 16384 + 8192 + wc * 2048 + fragoff;
        bf16x8 af[8], b0, b1;
#pragma unroll
        for (int mf = 0; mf < 8; ++mf) af[mf] = *(const bf16x8*)(Ab + mf * 512);
        b0 = *(const bf16x8*)(Bb);
        b1 = *(const bf16x8*)(Bb + 512);
        if (dostage) stageA(tstage & 3, tstage);
        __builtin_amdgcn_s_setprio(1);
#pragma unroll
        for (int mf = 0; mf < 8; ++mf) {
            acc[mf][0] = MFMA16(af[mf], b0, acc[mf][0]);
            acc[mf][1] = MFMA16(af[mf], b1, acc[mf][1]);
        }
        __builtin_amdgcn_s_setprio(0);
        b0 = *(const bf16x8*)(Bb + 1024);
        b1 = *(const bf16x8*)(Bb + 1536);
        if (dostage) stageB(tstage & 3, tstage);
        __builtin_amdgcn_s_setprio(1);
#pragma unroll
        for (int mf = 0; mf < 8; ++mf) {
            acc[mf][2] = MFMA16(af[mf], b0, acc[mf][2]);
            acc[mf][3] = MFMA16(af[mf], b1, acc[mf][3]);
        }
        __builtin_amdgcn_s_setprio(0);
    };

    stageA(0, 0); stageB(0, 0);
    stageA(1, 1); stageB(1, 1);
    stageA(2, 2); stageB(2, 2);
    asm volatile("s_waitcnt vmcnt(8)" ::: "memory");
    __builtin_amdgcn_s_barrier();
    __builtin_amdgcn_sched_barrier(0);

    for (int t = 0; t < NT - 3; ++t) {
        doTile(t & 3, t + 3, true);
        asm volatile("s_waitcnt vmcnt(8)" ::: "memory");
        __builtin_amdgcn_s_barrier();
        __builtin_amdgcn_sched_barrier(0);
    }
    doTile((NT - 3) & 3, 0, false);
    asm volatile("s_waitcnt vmcnt(4)" ::: "memory");
    __builtin_amdgcn_s_barrier();
    __builtin_amdgcn_sched_barrier(0);
    doTile((NT - 2) & 3, 0, false);
    asm volatile("s_waitcnt vmcnt(0)" ::: "memory");
    __builtin_amdgcn_s_barrier();
    __builtin_amdgcn_sched_barrier(0);
    doTile((NT - 1) & 3, 0, false);

    const int bnbase = bn * 256 + wc * 64;
#pragma unroll
    for (int nf = 0; nf < 4; ++nf) {
        int cg = bnbase + nf * 16 + l15;
        float bv = bias[cg];
        int which = cg >> 10, rem = cg & 1023;
        u16* dst = (which == 0) ? qb : (which == 1) ? kb : vb;
        float qs = (which == 0) ? 0.18033688011112042f : 1.0f;
        size_t colterm = (size_t)(rem >> 6) * 131072 + (size_t)(rem & 63);
#pragma unroll
        for (int mf = 0; mf < 8; ++mf) {
            int rgb = bm * 256 + wr * 128 + mf * 16 + lhi * 4;
            size_t rowterm = (size_t)(rgb >> 11) * 2097152 + (size_t)(rgb & 2047) * 64;
#pragma unroll
            for (int v = 0; v < 4; ++v) {
                float val = (acc[mf][nf][v] + bv) * qs;
                dst[rowterm + (size_t)v * 64 + colterm] = f2bf(val);
            }
        }
    }
}

// ---------------------------------------------------------------------------
// Output projection GEMM (128x128, verified structure).
__global__ __launch_bounds__(256) void gemm_bt(
    const u16* __restrict__ A, const u16* __restrict__ Bt, const float* __restrict__ bias,
    int M, int N, int K, float* __restrict__ outf) {
    __shared__ u16 Al[128 * 32];
    __shared__ u16 Bl[128 * 32];
    const int bm = blockIdx.x, bn = blockIdx.y;
    const int tid = threadIdx.x, wid = tid >> 6, lane = tid & 63;
    const int wr = wid >> 1, wc = wid & 1;
    const int l15 = lane & 15, lhi = lane >> 4;

    f32x4 acc[4][4];
#pragma unroll
    for (int i = 0; i < 4; ++i)
#pragma unroll
        for (int j = 0; j < 4; ++j) acc[i][j] = (f32x4){0.f, 0.f, 0.f, 0.f};

    for (int k0 = 0; k0 < K; k0 += 32) {
        __syncthreads();
#pragma unroll
        for (int s = 0; s < 2; ++s) {
            int lin0 = (wid * 2 + s) * 1024;
            int off = lin0 + lane * 16;
            int row = off >> 6, colb = off & 63;
            const u16* ga = A + (size_t)(bm * 128 + row) * K + k0 + (colb >> 1);
            gload16(ga, (char*)Al + lin0);
            const u16* gb = Bt + (size_t)(bn * 128 + row) * K + k0 + (colb >> 1);
            gload16(gb, (char*)Bl + lin0);
        }
        __syncthreads();
        bf16x8 af[4], bfr[4];
#pragma unroll
        for (int mt = 0; mt < 4; ++mt)
            af[mt] = *(const bf16x8*)&Al[(wr * 64 + mt * 16 + l15) * 32 + lhi * 8];
#pragma unroll
        for (int nt = 0; nt < 4; ++nt)
            bfr[nt] = *(const bf16x8*)&Bl[(wc * 64 + nt * 16 + l15) * 32 + lhi * 8];
#pragma unroll
        for (int mt = 0; mt < 4; ++mt)
#pragma unroll
            for (int nt = 0; nt < 4; ++nt)
                acc[mt][nt] = MFMA16(af[mt], bfr[nt], acc[mt][nt]);
    }

#pragma unroll
    for (int mt = 0; mt < 4; ++mt)
#pragma unroll
        for (int nt = 0; nt < 4; ++nt)
#pragma unroll
            for (int v = 0; v < 4; ++v) {
                int rg = bm * 128 + wr * 64 + mt * 16 + lhi * 4 + v;
                int cg = bn * 128 + wc * 64 + nt * 16 + l15;
                outf[(size_t)rg * N + cg] = acc[mt][nt][v] + bias[cg];
            }
}

// ---------------------------------------------------------------------------
// Flash attention fwd, causal — 16x16x32 swapped-operand (math verified r5/r7).
// Round 8: one block = one 128-q chunk (4 waves x 32 q, 2 groups sharing K/V
// fragment reads). Grid 1024 = 16 chunks x 64 bh -> 4 blocks/CU (restores TLP
// lost in r7's pairing). Longest chunks launched first (backfill balance);
// XCD clustering: the 16 blocks of each bh share one XCD's L2.
__global__ __launch_bounds__(256, 4) void attn_kernel(
    const u16* __restrict__ qbuf, const u16* __restrict__ kbuf,
    const u16* __restrict__ vtb, u16* __restrict__ obuf) {
    __shared__ u16 Kl[2][64 * 64];
    __shared__ u16 Vl[2][64 * 64];
    const int bid = blockIdx.x;
    const int idx = bid >> 3;
    const int c = 15 - (idx >> 3);               // chunk index, longest (15) first
    const int bh = ((bid & 7) << 3) + (idx & 7); // XCD-clustered
    const int b = bh >> 4, h = bh & 15;
    const int tid = threadIdx.x, wid = tid >> 6, lane = tid & 63;
    const int l15 = lane & 15, lhi = lane >> 4;
    const int q0 = c * 128 + wid * 32;           // groups at +0, +16
    const int ntW = 2 * c + (wid >> 1) + 1;      // tiles this wave computes
    const int ntmax = 2 * c + 2;

    auto loadQ = [&](int qbase, bf16x8* dst) {
        const u16* qp = qbuf + ((size_t)bh * 2048 + qbase + l15) * 64 + lhi * 8;
        dst[0] = *(const bf16x8*)(qp);
        dst[1] = *(const bf16x8*)(qp + 32);
    };
    bf16x8 qf0[2], qf1[2];
    loadQ(q0, qf0); loadQ(q0 + 16, qf1);

    float m0 = -1e30f, l0 = 0.f, m1 = -1e30f, l1 = 0.f;
    f32x4 o0[4], o1[4];
#pragma unroll
    for (int d = 0; d < 4; ++d) {
        o0[d] = (f32x4){0.f, 0.f, 0.f, 0.f};
        o1[d] = (f32x4){0.f, 0.f, 0.f, 0.f};
    }

    const int srow = lane >> 3;
    const int scolb = ((lane & 7) * 16) ^ (srow << 4);

    auto stage = [&](int buf, int t) {
        const int kbase = t * 64;
#pragma unroll
        for (int s = 0; s < 2; ++s) {
            int sg = wid * 2 + s;
            int row = sg * 8 + srow;
            const u16* gk = kbuf + ((size_t)bh * 2048 + kbase + row) * 64 + (scolb >> 1);
            gload16(gk, (char*)Kl[buf] + sg * 1024);
            const u16* gv = vtb + ((size_t)bh * 64 + row) * 2048 + kbase + (scolb >> 1);
            gload16(gv, (char*)Vl[buf] + sg * 1024);
        }
    };

    // masking + online softmax + P-pack for one 16-q group (defer-max THR=8)
    auto smax = [&](f32x4* s, int qg0, int t, float& m, float& l, f32x4* oa, u32* pw) {
        const int qg = qg0 + l15;
        if (64 * t + 63 > qg0) {
#pragma unroll
            for (int kb4 = 0; kb4 < 4; ++kb4)
#pragma unroll
                for (int v = 0; v < 4; ++v) {
                    int kg = 64 * t + kb4 * 16 + lhi * 4 + v;
                    if (kg > qg) s[kb4][v] = -1e30f;
                }
        }
        float pm = fmaxf(fmaxf(fmaxf(s[0][0], s[0][1]), fmaxf(s[0][2], s[0][3])),
                         fmaxf(fmaxf(s[1][0], s[1][1]), fmaxf(s[1][2], s[1][3])));
        pm = fmaxf(pm, fmaxf(fmaxf(fmaxf(s[2][0], s[2][1]), fmaxf(s[2][2], s[2][3])),
                             fmaxf(fmaxf(s[3][0], s[3][1]), fmaxf(s[3][2], s[3][3]))));
        pm = fmaxf(pm, __shfl_xor(pm, 16, 64));
        pm = fmaxf(pm, __shfl_xor(pm, 32, 64));
        if (!__all(pm <= m + 8.f)) {
            float nm = fmaxf(m, pm);
            float f = exp2f(m - nm);
            m = nm;
            l *= f;
#pragma unroll
            for (int d = 0; d < 4; ++d)
#pragma unroll
                for (int v = 0; v < 4; ++v) oa[d][v] *= f;
        }
        float rs = 0.f;
#pragma unroll
        for (int kb4 = 0; kb4 < 4; ++kb4)
#pragma unroll
            for (int v = 0; v < 4; ++v) {
                float e = exp2f(s[kb4][v] - m);
                s[kb4][v] = e;
                rs += e;
            }
        rs += __shfl_xor(rs, 16, 64);
        rs += __shfl_xor(rs, 32, 64);
        l += rs;
        pw[0] = pkbf(s[0][0], s[0][1]); pw[1] = pkbf(s[0][2], s[0][3]);
        pw[2] = pkbf(s[1][0], s[1][1]); pw[3] = pkbf(s[1][2], s[1][3]);
        pw[4] = pkbf(s[2][0], s[2][1]); pw[5] = pkbf(s[2][2], s[2][3]);
        pw[6] = pkbf(s[3][0], s[3][1]); pw[7] = pkbf(s[3][2], s[3][3]);
    };

    // 2 groups vs tile t; K/V fragments read once, used twice
    auto computeChunk = [&](const char* Kb, const char* Vb, int t) {
        f32x4 s0[4], s1[4];
        __builtin_amdgcn_s_setprio(1);
#pragma unroll
        for (int kb4 = 0; kb4 < 4; ++kb4) {
            const int r = kb4 * 16 + l15;
            const int sw = (r & 7) << 4;
            const int rowb = r * 128;
            bf16x8 kf0 = *(const bf16x8*)(Kb + rowb + ((lhi * 16) ^ sw));
            bf16x8 kf1 = *(const bf16x8*)(Kb + rowb + ((64 + lhi * 16) ^ sw));
            f32x4 a0 = (f32x4){0.f, 0.f, 0.f, 0.f};
            a0 = MFMA16(kf0, qf0[0], a0);
            a0 = MFMA16(kf1, qf0[1], a0);
            s0[kb4] = a0;
            f32x4 a1 = (f32x4){0.f, 0.f, 0.f, 0.f};
            a1 = MFMA16(kf0, qf1[0], a1);
            a1 = MFMA16(kf1, qf1[1], a1);
            s1[kb4] = a1;
        }
        __builtin_amdgcn_s_setprio(0);
        u32 pw0[8], pw1[8];
        smax(s0, q0, t, m0, l0, o0, pw0);
        smax(s1, q0 + 16, t, m1, l1, o1, pw1);
        __builtin_amdgcn_s_setprio(1);
#pragma unroll
        for (int ks = 0; ks < 2; ++ks) {
            bf16x8 pb0 = __builtin_bit_cast(bf16x8,
                (u32x4){pw0[ks * 4 + 0], pw0[ks * 4 + 1], pw0[ks * 4 + 2], pw0[ks * 4 + 3]});
            bf16x8 pb1 = __builtin_bit_cast(bf16x8,
                (u32x4){pw1[ks * 4 + 0], pw1[ks * 4 + 1], pw1[ks * 4 + 2], pw1[ks * 4 + 3]});
#pragma unroll
            for (int dhb = 0; dhb < 4; ++dhb) {
                const int r = dhb * 16 + l15;
                const int sw = (r & 7) << 4;
                u16x4 v0 = *(const u16x4*)(Vb + r * 128 + ((ks * 64 + 8 * lhi) ^ sw));
                u16x4 v1 = *(const u16x4*)(Vb + r * 128 + ((ks * 64 + 32 + 8 * lhi) ^ sw));
                u16x8 vv = {v0[0], v0[1], v0[2], v0[3], v1[0], v1[1], v1[2], v1[3]};
                bf16x8 vf = __builtin_bit_cast(bf16x8, vv);
                o0[dhb] = MFMA16(vf, pb0, o0[dhb]);
                o1[dhb] = MFMA16(vf, pb1, o1[dhb]);
            }
        }
        __builtin_amdgcn_s_setprio(0);
    };

    stage(0, 0);
    int t = 0;
    for (;;) {
        __syncthreads();
        if (t + 1 < ntmax) stage(1, t + 1);
        if (t < ntW) computeChunk((const char*)Kl[0], (const char*)Vl[0], t);
        if (++t == ntmax) break;
        __syncthreads();
        if (t + 1 < ntmax) stage(0, t + 1);
        if (t < ntW) computeChunk((const char*)Kl[1], (const char*)Vl[1], t);
        if (++t == ntmax) break;
    }

    auto epi = [&](int qg0, float l, const f32x4* oa) {
        const float rl = 1.f / l;
        const int q = qg0 + l15;
        const size_t rowoff = ((size_t)b * 2048 + q) * 1024 + h * 64;
#pragma unroll
        for (int dhb = 0; dhb < 4; ++dhb) {
            u16x4 w;
#pragma unroll
            for (int v = 0; v < 4; ++v) w[v] = f2bf(oa[dhb][v] * rl);
            *(u16x4*)&obuf[rowoff + dhb * 16 + lhi * 4] = w;
        }
    };
    epi(q0, l0, o0);
    epi(q0 + 16, l1, o1);
}

// ---------------------------------------------------------------------------
extern "C" void kernel_launch(void* const* d_in, const int* in_sizes, int n_in,
                              void* d_out, int out_size, void* d_ws, size_t ws_size,
                              hipStream_t stream) {
    const float* inp   = (const float*)d_in[0];   // [4,2048,1024]
    const float* W_qkv = (const float*)d_in[1];   // [1024,3072]
    const float* b_qkv = (const float*)d_in[2];   // [3072]
    const float* W_out = (const float*)d_in[3];   // [1024,1024]
    const float* b_out = (const float*)d_in[4];   // [1024]
    float* out = (float*)d_out;                   // [4,2048,1024] f32

    u16* xb   = (u16*)d_ws;          // 8192x1024
    u16* wqt  = xb + 8388608;        // 3072x1024
    u16* wot  = wqt + 3145728;       // 1024x1024
    u16* qbuf = wot + 1048576;       // [64][2048][64]
    u16* kbuf = qbuf + 8388608;
    u16* vbuf = kbuf + 8388608;
    u16* vtb  = vbuf + 8388608;      // [64][64][2048]
    u16* obuf = vtb + 8388608;       // 8192x1024

    convert_f32_bf16<<<8192, 256, 0, stream>>>(inp, xb, 2097152);
    transpose_convert<<<dim3(16, 48), 256, 0, stream>>>(W_qkv, wqt, 1024, 3072);
    transpose_convert<<<dim3(16, 16), 256, 0, stream>>>(W_out, wot, 1024, 1024);
    gemm256_qkv<<<384, 512, 0, stream>>>(xb, wqt, b_qkv, qbuf, kbuf, vbuf);
    transpose_v<<<dim3(32, 64), 256, 0, stream>>>(vbuf, vtb);
    attn_kernel<<<1024, 256, 0, stream>>>(qbuf, kbuf, vtb, obuf);
    gemm_bt<<<dim3(64, 8), 256, 0, stream>>>(obuf, wot, b_out, 8192, 1024, 1024, out);
}

// Round 9
// 185.342 us; speedup vs baseline: 2.3968x; 1.0357x over previous
//
#include <hip/hip_runtime.h>
#include <hip/hip_bf16.h>

typedef unsigned short u16;
typedef unsigned u32;
typedef __attribute__((ext_vector_type(4))) unsigned short u16x4;
typedef __attribute__((ext_vector_type(8))) unsigned short u16x8;
typedef __attribute__((ext_vector_type(4))) unsigned u32x4;
typedef __attribute__((ext_vector_type(8))) __bf16 bf16x8;
typedef __attribute__((ext_vector_type(4))) float f32x4;

typedef __attribute__((address_space(1))) void as1v;
typedef __attribute__((address_space(3))) void as3v;

#define MFMA16(a, b, c) __builtin_amdgcn_mfma_f32_16x16x32_bf16(a, b, c, 0, 0, 0)

#if __has_builtin(__builtin_amdgcn_permlane16_swap) && __has_builtin(__builtin_amdgcn_permlane32_swap)
#define HAVE_PERMLANE_SWAP 1
#else
#define HAVE_PERMLANE_SWAP 0
#endif

__device__ __forceinline__ u16 f2bf(float f) {
    unsigned u = __builtin_bit_cast(unsigned, f);
    u += 0x7fffu + ((u >> 16) & 1u);
    return (u16)(u >> 16);
}

__device__ __forceinline__ u32 pkbf(float lo, float hi) {
    u32 r;
    asm("v_cvt_pk_bf16_f32 %0, %1, %2" : "=v"(r) : "v"(lo), "v"(hi));
    return r;
}

__device__ __forceinline__ void gload16(const void* g, void* l) {
    __builtin_amdgcn_global_load_lds((as1v*)g, (as3v*)l, 16, 0, 0);
}

// cross-lane reduce over lanes {l, l^16, l^32, l^48} — direction-proof:
// permlaneN_swap(x,x) yields {r0[l], r1[l]} = {x[l], x[l^N]} as a set.
__device__ __forceinline__ float redmax_cross(float v) {
#if HAVE_PERMLANE_SWAP
    u32 xu = __builtin_bit_cast(u32, v);
    auto r16 = __builtin_amdgcn_permlane16_swap(xu, xu, false, false);
    float a = fmaxf(__builtin_bit_cast(float, (u32)r16[0]),
                    __builtin_bit_cast(float, (u32)r16[1]));
    u32 au = __builtin_bit_cast(u32, a);
    auto r32 = __builtin_amdgcn_permlane32_swap(au, au, false, false);
    return fmaxf(__builtin_bit_cast(float, (u32)r32[0]),
                 __builtin_bit_cast(float, (u32)r32[1]));
#else
    v = fmaxf(v, __shfl_xor(v, 16, 64));
    return fmaxf(v, __shfl_xor(v, 32, 64));
#endif
}

__device__ __forceinline__ float redsum_cross(float v) {
#if HAVE_PERMLANE_SWAP
    u32 xu = __builtin_bit_cast(u32, v);
    auto r16 = __builtin_amdgcn_permlane16_swap(xu, xu, false, false);
    float a = __builtin_bit_cast(float, (u32)r16[0]) +
              __builtin_bit_cast(float, (u32)r16[1]);
    u32 au = __builtin_bit_cast(u32, a);
    auto r32 = __builtin_amdgcn_permlane32_swap(au, au, false, false);
    return __builtin_bit_cast(float, (u32)r32[0]) +
           __builtin_bit_cast(float, (u32)r32[1]);
#else
    v += __shfl_xor(v, 16, 64);
    return v + __shfl_xor(v, 32, 64);
#endif
}

// ---------------------------------------------------------------------------
__global__ void convert_f32_bf16(const float* __restrict__ in, u16* __restrict__ out, int n4) {
    int i = blockIdx.x * blockDim.x + threadIdx.x;
    if (i < n4) {
        float4 v = *(const float4*)&in[(size_t)i * 4];
        u16x4 o;
        o.x = f2bf(v.x); o.y = f2bf(v.y); o.z = f2bf(v.z); o.w = f2bf(v.w);
        *(u16x4*)&out[(size_t)i * 4] = o;
    }
}

// ---------------------------------------------------------------------------
__global__ void transpose_convert(const float* __restrict__ in, u16* __restrict__ out, int R, int C) {
    __shared__ float tl[64][65];
    const int rb = blockIdx.x, cb = blockIdx.y;
    const int tid = threadIdx.x;
    for (int it = 0; it < 4; ++it) {
        int lin = (tid + it * 256) * 4;
        int r = lin >> 6, c = lin & 63;
        float4 v = *(const float4*)&in[(size_t)(rb * 64 + r) * C + cb * 64 + c];
        tl[r][c + 0] = v.x; tl[r][c + 1] = v.y; tl[r][c + 2] = v.z; tl[r][c + 3] = v.w;
    }
    __syncthreads();
    for (int it = 0; it < 4; ++it) {
        int lin = (tid + it * 256) * 4;
        int oc = lin >> 6, orr = lin & 63;
        u16x4 o;
        o.x = f2bf(tl[orr + 0][oc]);
        o.y = f2bf(tl[orr + 1][oc]);
        o.z = f2bf(tl[orr + 2][oc]);
        o.w = f2bf(tl[orr + 3][oc]);
        *(u16x4*)&out[(size_t)(cb * 64 + oc) * R + rb * 64 + orr] = o;
    }
}

// ---------------------------------------------------------------------------
__global__ void transpose_v(const u16* __restrict__ vbuf, u16* __restrict__ vtb) {
    __shared__ u16 tl[64][65];
    const int nb = blockIdx.x, bh = blockIdx.y;
    const int tid = threadIdx.x;
    for (int it = 0; it < 2; ++it) {
        int lin = (tid + it * 256) * 8;
        int nl = lin >> 6, dh = lin & 63;
        u16x8 v = *(const u16x8*)&vbuf[((size_t)bh * 2048 + nb * 64 + nl) * 64 + dh];
#pragma unroll
        for (int j = 0; j < 8; ++j) tl[dh + j][nl] = v[j];
    }
    __syncthreads();
    for (int it = 0; it < 2; ++it) {
        int lin = (tid + it * 256) * 8;
        int dh = lin >> 6, nl = lin & 63;
        u16x8 o;
#pragma unroll
        for (int j = 0; j < 8; ++j) o[j] = tl[dh][nl + j];
        *(u16x8*)&vtb[((size_t)bh * 64 + dh) * 2048 + nb * 64 + nl] = o;
    }
}

// ---------------------------------------------------------------------------
// QKV projection GEMM, deep-pipelined (verified r6). M=8192,N=3072,K=1024.
__global__ __launch_bounds__(512, 2) void gemm256_qkv(
    const u16* __restrict__ A, const u16* __restrict__ Bt, const float* __restrict__ bias,
    u16* __restrict__ qb, u16* __restrict__ kb, u16* __restrict__ vb) {
    constexpr int K = 1024;
    constexpr int NT = 32;
    __shared__ u16 ldsu[65536];

    const int bid = blockIdx.x;
    const int swz = (bid & 7) * 48 + (bid >> 3);
    const int bm = swz / 12, bn = swz % 12;

    const int tid = threadIdx.x, wid = tid >> 6, lane = tid & 63;
    const int wr = wid >> 2, wc = wid & 3;
    const int l15 = lane & 15, lhi = lane >> 4;

    const int sslot = (lane & 7) ^ (lane >> 3);
    const int kcol = (sslot & 3) * 8;
    const int mloc = (lane >> 3) * 2 + (sslot >> 2);

    const u16* Arow[2];
    const u16* Brow[2];
#pragma unroll
    for (int li = 0; li < 2; ++li) {
        int sg = wid * 2 + li;
        int m = sg * 16 + mloc;
        Arow[li] = A + (size_t)(bm * 256 + m) * K + kcol;
        Brow[li] = Bt + (size_t)(bn * 256 + m) * K + kcol;
    }

    auto stageA = [&](int buf, int t) {
#pragma unroll
        for (int li = 0; li < 2; ++li) {
            int sg = wid * 2 + li;
            gload16(Arow[li] + t * 32, (char*)ldsu + buf * 32768 + sg * 1024);
        }
    };
    auto stageB = [&](int buf, int t) {
#pragma unroll
        for (int li = 0; li < 2; ++li) {
            int sg = wid * 2 + li;
            gload16(Brow[li] + t * 32, (char*)ldsu + buf * 32768 + 16384 + sg * 1024);
        }
    };

    const int rslot = ((l15 & 1) * 4 + lhi) ^ ((l15 >> 1) & 7);
    const int fragoff = (l15 >> 1) * 64 + rslot * 8;

    f32x4 acc[8][4];
#pragma unroll
    for (int i = 0; i < 8; ++i)
#pragma unroll
        for (int j = 0; j < 4; ++j) acc[i][j] = (f32x4){0.f, 0.f, 0.f, 0.f};

    auto doTile = [&](int cur, int tstage, bool dostage) {
        const u16* Ab = ldsu + cur * 16384 + wr * 4096 + fragoff;
        const u16* Bb = ldsu + cur * 16384 + 8192 + wc * 2048 + fragoff;
        bf16x8 af[8], b0, b1;
#pragma unroll
        for (int mf = 0; mf < 8; ++mf) af[mf] = *(const bf16x8*)(Ab + mf * 512);
        b0 = *(const bf16x8*)(Bb);
        b1 = *(const bf16x8*)(Bb + 512);
        if (dostage) stageA(tstage & 3, tstage);
        __builtin_amdgcn_s_setprio(1);
#pragma unroll
        for (int mf = 0; mf < 8; ++mf) {
            acc[mf][0] = MFMA16(af[mf], b0, acc[mf][0]);
            acc[mf][1] = MFMA16(af[mf], b1, acc[mf][1]);
        }
        __builtin_amdgcn_s_setprio(0);
        b0 = *(const bf16x8*)(Bb + 1024);
        b1 = *(const bf16x8*)(Bb + 1536);
        if (dostage) stageB(tstage & 3, tstage);
        __builtin_amdgcn_s_setprio(1);
#pragma unroll
        for (int mf = 0; mf < 8; ++mf) {
            acc[mf][2] = MFMA16(af[mf], b0, acc[mf][2]);
            acc[mf][3] = MFMA16(af[mf], b1, acc[mf][3]);
        }
        __builtin_amdgcn_s_setprio(0);
    };

    stageA(0, 0); stageB(0, 0);
    stageA(1, 1); stageB(1, 1);
    stageA(2, 2); stageB(2, 2);
    asm volatile("s_waitcnt vmcnt(8)" ::: "memory");
    __builtin_amdgcn_s_barrier();
    __builtin_amdgcn_sched_barrier(0);

    for (int t = 0; t < NT - 3; ++t) {
        doTile(t & 3, t + 3, true);
        asm volatile("s_waitcnt vmcnt(8)" ::: "memory");
        __builtin_amdgcn_s_barrier();
        __builtin_amdgcn_sched_barrier(0);
    }
    doTile((NT - 3) & 3, 0, false);
    asm volatile("s_waitcnt vmcnt(4)" ::: "memory");
    __builtin_amdgcn_s_barrier();
    __builtin_amdgcn_sched_barrier(0);
    doTile((NT - 2) & 3, 0, false);
    asm volatile("s_waitcnt vmcnt(0)" ::: "memory");
    __builtin_amdgcn_s_barrier();
    __builtin_amdgcn_sched_barrier(0);
    doTile((NT - 1) & 3, 0, false);

    const int bnbase = bn * 256 + wc * 64;
#pragma unroll
    for (int nf = 0; nf < 4; ++nf) {
        int cg = bnbase + nf * 16 + l15;
        float bv = bias[cg];
        int which = cg >> 10, rem = cg & 1023;
        u16* dst = (which == 0) ? qb : (which == 1) ? kb : vb;
        float qs = (which == 0) ? 0.18033688011112042f : 1.0f;
        size_t colterm = (size_t)(rem >> 6) * 131072 + (size_t)(rem & 63);
#pragma unroll
        for (int mf = 0; mf < 8; ++mf) {
            int rgb = bm * 256 + wr * 128 + mf * 16 + lhi * 4;
            size_t rowterm = (size_t)(rgb >> 11) * 2097152 + (size_t)(rgb & 2047) * 64;
#pragma unroll
            for (int v = 0; v < 4; ++v) {
                float val = (acc[mf][nf][v] + bv) * qs;
                dst[rowterm + (size_t)v * 64 + colterm] = f2bf(val);
            }
        }
    }
}

// ---------------------------------------------------------------------------
// Output projection GEMM, deep-pipelined 256x128 tile. M=8192,N=1024,K=1024.
// 8 waves (2M x 4N); wave tile 128x32. LDS: 4-deep x (A 16KB + B 8KB) = 96KB.
// 3 loads/tile/wave -> steady vmcnt(6), tail 3 -> 0. Grid 256 = 1 block/CU.
__global__ __launch_bounds__(512, 2) void gemm256_out(
    const u16* __restrict__ A, const u16* __restrict__ Bt, const float* __restrict__ bias,
    float* __restrict__ outf) {
    constexpr int K = 1024;
    constexpr int NT = 32;
    __shared__ u16 ldsu[49152];   // 96 KB

    const int bid = blockIdx.x;
    const int swz = (bid & 7) * 32 + (bid >> 3);   // XCD-contiguous bm
    const int bm = swz >> 3, bn = swz & 7;

    const int tid = threadIdx.x, wid = tid >> 6, lane = tid & 63;
    const int wr = wid >> 2, wc = wid & 3;
    const int l15 = lane & 15, lhi = lane >> 4;

    const int sslot = (lane & 7) ^ (lane >> 3);
    const int kcol = (sslot & 3) * 8;
    const int mloc = (lane >> 3) * 2 + (sslot >> 2);

    const u16* Arow[2];
#pragma unroll
    for (int li = 0; li < 2; ++li) {
        int sg = wid * 2 + li;
        Arow[li] = A + (size_t)(bm * 256 + sg * 16 + mloc) * K + kcol;
    }
    const u16* Brow = Bt + (size_t)(bn * 128 + wid * 16 + mloc) * K + kcol;

    auto stageA = [&](int buf, int t) {
#pragma unroll
        for (int li = 0; li < 2; ++li) {
            int sg = wid * 2 + li;
            gload16(Arow[li] + t * 32, (char*)ldsu + buf * 24576 + sg * 1024);
        }
    };
    auto stageB = [&](int buf, int t) {
        gload16(Brow + t * 32, (char*)ldsu + buf * 24576 + 16384 + wid * 1024);
    };

    const int rslot = ((l15 & 1) * 4 + lhi) ^ ((l15 >> 1) & 7);
    const int fragoff = (l15 >> 1) * 64 + rslot * 8;

    f32x4 acc[8][2];
#pragma unroll
    for (int i = 0; i < 8; ++i) {
        acc[i][0] = (f32x4){0.f, 0.f, 0.f, 0.f};
        acc[i][1] = (f32x4){0.f, 0.f, 0.f, 0.f};
    }

    auto doTile = [&](int cur, int tstage, bool dostage) {
        const u16* Ab = ldsu + cur * 12288 + wr * 4096 + fragoff;
        const u16* Bb = ldsu + cur * 12288 + 8192 + wc * 1024 + fragoff;
        bf16x8 af[8], b0, b1;
#pragma unroll
        for (int mf = 0; mf < 8; ++mf) af[mf] = *(const bf16x8*)(Ab + mf * 512);
        b0 = *(const bf16x8*)(Bb);
        b1 = *(const bf16x8*)(Bb + 512);
        if (dostage) stageA(tstage & 3, tstage);
        __builtin_amdgcn_s_setprio(1);
#pragma unroll
        for (int mf = 0; mf < 8; ++mf) acc[mf][0] = MFMA16(af[mf], b0, acc[mf][0]);
        __builtin_amdgcn_s_setprio(0);
        if (dostage) stageB(tstage & 3, tstage);
        __builtin_amdgcn_s_setprio(1);
#pragma unroll
        for (int mf = 0; mf < 8; ++mf) acc[mf][1] = MFMA16(af[mf], b1, acc[mf][1]);
        __builtin_amdgcn_s_setprio(0);
    };

    stageA(0, 0); stageB(0, 0);
    stageA(1, 1); stageB(1, 1);
    stageA(2, 2); stageB(2, 2);
    asm volatile("s_waitcnt vmcnt(6)" ::: "memory");
    __builtin_amdgcn_s_barrier();
    __builtin_amdgcn_sched_barrier(0);

    for (int t = 0; t < NT - 3; ++t) {
        doTile(t & 3, t + 3, true);
        asm volatile("s_waitcnt vmcnt(6)" ::: "memory");
        __builtin_amdgcn_s_barrier();
        __builtin_amdgcn_sched_barrier(0);
    }
    doTile((NT - 3) & 3, 0, false);
    asm volatile("s_waitcnt vmcnt(3)" ::: "memory");
    __builtin_amdgcn_s_barrier();
    __builtin_amdgcn_sched_barrier(0);
    doTile((NT - 2) & 3, 0, false);
    asm volatile("s_waitcnt vmcnt(0)" ::: "memory");
    __builtin_amdgcn_s_barrier();
    __builtin_amdgcn_sched_barrier(0);
    doTile((NT - 1) & 3, 0, false);

#pragma unroll
    for (int nf = 0; nf < 2; ++nf) {
        int cg = bn * 128 + wc * 32 + nf * 16 + l15;
        float bv = bias[cg];
#pragma unroll
        for (int mf = 0; mf < 8; ++mf) {
            int rgb = bm * 256 + wr * 128 + mf * 16 + lhi * 4;
#pragma unroll
            for (int v = 0; v < 4; ++v)
                outf[(size_t)(rgb + v) * 1024 + cg] = acc[mf][nf][v] + bv;
        }
    }
}

// ---------------------------------------------------------------------------
// Flash attention fwd, causal — 16x16x32 swapped-operand (math verified r5/r7/r8).
// Round 9: (1) balanced chunk->block map: every CU's 4-block sequence sums to
// 30 tile-rounds (was 24..40); (2) permlane16/32_swap reduces (VALU) replace
// ds shfl_xor on the softmax critical chain. Rest identical to r8.
__global__ __launch_bounds__(256, 4) void attn_kernel(
    const u16* __restrict__ qbuf, const u16* __restrict__ kbuf,
    const u16* __restrict__ vtb, u16* __restrict__ obuf) {
    __shared__ u16 Kl[2][64 * 64];
    __shared__ u16 Vl[2][64 * 64];
    const int bid = blockIdx.x;
    const int rr = bid >> 8;                     // dispatch round 0..3
    const int pp = (bid >> 6) & 3;               // position-in-round 0..3
    const int c = (rr & 1) ? (((rr >> 1) << 2) + pp)
                           : (15 - ((rr >> 1) << 2) - pp);
    const int bh = ((bid & 7) << 3) + ((bid >> 3) & 7); // XCD-clustered
    const int b = bh >> 4, h = bh & 15;
    const int tid = threadIdx.x, wid = tid >> 6, lane = tid & 63;
    const int l15 = lane & 15, lhi = lane >> 4;
    const int q0 = c * 128 + wid * 32;           // groups at +0, +16
    const int ntW = 2 * c + (wid >> 1) + 1;      // tiles this wave computes
    const int ntmax = 2 * c + 2;

    auto loadQ = [&](int qbase, bf16x8* dst) {
        const u16* qp = qbuf + ((size_t)bh * 2048 + qbase + l15) * 64 + lhi * 8;
        dst[0] = *(const bf16x8*)(qp);
        dst[1] = *(const bf16x8*)(qp + 32);
    };
    bf16x8 qf0[2], qf1[2];
    loadQ(q0, qf0); loadQ(q0 + 16, qf1);

    float m0 = -1e30f, l0 = 0.f, m1 = -1e30f, l1 = 0.f;
    f32x4 o0[4], o1[4];
#pragma unroll
    for (int d = 0; d < 4; ++d) {
        o0[d] = (f32x4){0.f, 0.f, 0.f, 0.f};
        o1[d] = (f32x4){0.f, 0.f, 0.f, 0.f};
    }

    const int srow = lane >> 3;
    const int scolb = ((lane & 7) * 16) ^ (srow << 4);

    auto stage = [&](int buf, int t) {
        const int kbase = t * 64;
#pragma unroll
        for (int s = 0; s < 2; ++s) {
            int sg = wid * 2 + s;
            int row = sg * 8 + srow;
            const u16* gk = kbuf + ((size_t)bh * 2048 + kbase + row) * 64 + (scolb >> 1);
            gload16(gk, (char*)Kl[buf] + sg * 1024);
            const u16* gv = vtb + ((size_t)bh * 64 + row) * 2048 + kbase + (scolb >> 1);
            gload16(gv, (char*)Vl[buf] + sg * 1024);
        }
    };

    // masking + online softmax + P-pack for one 16-q group (defer-max THR=8)
    auto smax = [&](f32x4* s, int qg0, int t, float& m, float& l, f32x4* oa, u32* pw) {
        const int qg = qg0 + l15;
        if (64 * t + 63 > qg0) {
#pragma unroll
            for (int kb4 = 0; kb4 < 4; ++kb4)
#pragma unroll
                for (int v = 0; v < 4; ++v) {
                    int kg = 64 * t + kb4 * 16 + lhi * 4 + v;
                    if (kg > qg) s[kb4][v] = -1e30f;
                }
        }
        float pm = fmaxf(fmaxf(fmaxf(s[0][0], s[0][1]), fmaxf(s[0][2], s[0][3])),
                         fmaxf(fmaxf(s[1][0], s[1][1]), fmaxf(s[1][2], s[1][3])));
        pm = fmaxf(pm, fmaxf(fmaxf(fmaxf(s[2][0], s[2][1]), fmaxf(s[2][2], s[2][3])),
                             fmaxf(fmaxf(s[3][0], s[3][1]), fmaxf(s[3][2], s[3][3]))));
        pm = redmax_cross(pm);
        if (!__all(pm <= m + 8.f)) {
            float nm = fmaxf(m, pm);
            float f = exp2f(m - nm);
            m = nm;
            l *= f;
#pragma unroll
            for (int d = 0; d < 4; ++d)
#pragma unroll
                for (int v = 0; v < 4; ++v) oa[d][v] *= f;
        }
        float rs = 0.f;
#pragma unroll
        for (int kb4 = 0; kb4 < 4; ++kb4)
#pragma unroll
            for (int v = 0; v < 4; ++v) {
                float e = exp2f(s[kb4][v] - m);
                s[kb4][v] = e;
                rs += e;
            }
        l += redsum_cross(rs);
        pw[0] = pkbf(s[0][0], s[0][1]); pw[1] = pkbf(s[0][2], s[0][3]);
        pw[2] = pkbf(s[1][0], s[1][1]); pw[3] = pkbf(s[1][2], s[1][3]);
        pw[4] = pkbf(s[2][0], s[2][1]); pw[5] = pkbf(s[2][2], s[2][3]);
        pw[6] = pkbf(s[3][0], s[3][1]); pw[7] = pkbf(s[3][2], s[3][3]);
    };

    // 2 groups vs tile t; K/V fragments read once, used twice
    auto computeChunk = [&](const char* Kb, const char* Vb, int t) {
        f32x4 s0[4], s1[4];
        __builtin_amdgcn_s_setprio(1);
#pragma unroll
        for (int kb4 = 0; kb4 < 4; ++kb4) {
            const int r = kb4 * 16 + l15;
            const int sw = (r & 7) << 4;
            const int rowb = r * 128;
            bf16x8 kf0 = *(const bf16x8*)(Kb + rowb + ((lhi * 16) ^ sw));
            bf16x8 kf1 = *(const bf16x8*)(Kb + rowb + ((64 + lhi * 16) ^ sw));
            f32x4 a0 = (f32x4){0.f, 0.f, 0.f, 0.f};
            a0 = MFMA16(kf0, qf0[0], a0);
            a0 = MFMA16(kf1, qf0[1], a0);
            s0[kb4] = a0;
            f32x4 a1 = (f32x4){0.f, 0.f, 0.f, 0.f};
            a1 = MFMA16(kf0, qf1[0], a1);
            a1 = MFMA16(kf1, qf1[1], a1);
            s1[kb4] = a1;
        }
        __builtin_amdgcn_s_setprio(0);
        u32 pw0[8], pw1[8];
        smax(s0, q0, t, m0, l0, o0, pw0);
        smax(s1, q0 + 16, t, m1, l1, o1, pw1);
        __builtin_amdgcn_s_setprio(1);
#pragma unroll
        for (int ks = 0; ks < 2; ++ks) {
            bf16x8 pb0 = __builtin_bit_cast(bf16x8,
                (u32x4){pw0[ks * 4 + 0], pw0[ks * 4 + 1], pw0[ks * 4 + 2], pw0[ks * 4 + 3]});
            bf16x8 pb1 = __builtin_bit_cast(bf16x8,
                (u32x4){pw1[ks * 4 + 0], pw1[ks * 4 + 1], pw1[ks * 4 + 2], pw1[ks * 4 + 3]});
#pragma unroll
            for (int dhb = 0; dhb < 4; ++dhb) {
                const int r = dhb * 16 + l15;
                const int sw = (r & 7) << 4;
                u16x4 v0 = *(const u16x4*)(Vb + r * 128 + ((ks * 64 + 8 * lhi) ^ sw));
                u16x4 v1 = *(const u16x4*)(Vb + r * 128 + ((ks * 64 + 32 + 8 * lhi) ^ sw));
                u16x8 vv = {v0[0], v0[1], v0[2], v0[3], v1[0], v1[1], v1[2], v1[3]};
                bf16x8 vf = __builtin_bit_cast(bf16x8, vv);
                o0[dhb] = MFMA16(vf, pb0, o0[dhb]);
                o1[dhb] = MFMA16(vf, pb1, o1[dhb]);
            }
        }
        __builtin_amdgcn_s_setprio(0);
    };

    stage(0, 0);
    int t = 0;
    for (;;) {
        __syncthreads();
        if (t + 1 < ntmax) stage(1, t + 1);
        if (t < ntW) computeChunk((const char*)Kl[0], (const char*)Vl[0], t);
        if (++t == ntmax) break;
        __syncthreads();
        if (t + 1 < ntmax) stage(0, t + 1);
        if (t < ntW) computeChunk((const char*)Kl[1], (const char*)Vl[1], t);
        if (++t == ntmax) break;
    }

    auto epi = [&](int qg0, float l, const f32x4* oa) {
        const float rl = 1.f / l;
        const int q = qg0 + l15;
        const size_t rowoff = ((size_t)b * 2048 + q) * 1024 + h * 64;
#pragma unroll
        for (int dhb = 0; dhb < 4; ++dhb) {
            u16x4 w;
#pragma unroll
            for (int v = 0; v < 4; ++v) w[v] = f2bf(oa[dhb][v] * rl);
            *(u16x4*)&obuf[rowoff + dhb * 16 + lhi * 4] = w;
        }
    };
    epi(q0, l0, o0);
    epi(q0 + 16, l1, o1);
}

// ---------------------------------------------------------------------------
extern "C" void kernel_launch(void* const* d_in, const int* in_sizes, int n_in,
                              void* d_out, int out_size, void* d_ws, size_t ws_size,
                              hipStream_t stream) {
    const float* inp   = (const float*)d_in[0];   // [4,2048,1024]
    const float* W_qkv = (const float*)d_in[1];   // [1024,3072]
    const float* b_qkv = (const float*)d_in[2];   // [3072]
    const float* W_out = (const float*)d_in[3];   // [1024,1024]
    const float* b_out = (const float*)d_in[4];   // [1024]
    float* out = (float*)d_out;                   // [4,2048,1024] f32

    u16* xb   = (u16*)d_ws;          // 8192x1024
    u16* wqt  = xb + 8388608;        // 3072x1024
    u16* wot  = wqt + 3145728;       // 1024x1024
    u16* qbuf = wot + 1048576;       // [64][2048][64]
    u16* kbuf = qbuf + 8388608;
    u16* vbuf = kbuf + 8388608;
    u16* vtb  = vbuf + 8388608;      // [64][64][2048]
    u16* obuf = vtb + 8388608;       // 8192x1024

    convert_f32_bf16<<<8192, 256, 0, stream>>>(inp, xb, 2097152);
    transpose_convert<<<dim3(16, 48), 256, 0, stream>>>(W_qkv, wqt, 1024, 3072);
    transpose_convert<<<dim3(16, 16), 256, 0, stream>>>(W_out, wot, 1024, 1024);
    gemm256_qkv<<<384, 512, 0, stream>>>(xb, wqt, b_qkv, qbuf, kbuf, vbuf);
    transpose_v<<<dim3(32, 64), 256, 0, stream>>>(vbuf, vtb);
    attn_kernel<<<1024, 256, 0, stream>>>(qbuf, kbuf, vtb, obuf);
    gemm256_out<<<256, 512, 0, stream>>>(obuf, wot, b_out, out);
}